// Round 4
// baseline (480.466 us; speedup 1.0000x reference)
//
#include <hip/hip_runtime.h>
#include <hip/hip_bf16.h>

// ShockPropagationGNN — round 17 (base: round 16, 478us; best 465us r13).
// - k_edgemlp4: one edge per 16-lane group, 16 edges/block, grid 12500.
//   Kills the 4-deep serial UV-gather chain (latency-bound: 25% occ, all
//   pipes idle). Same math/instruction mix per edge; LDS 24->9KB.
// - k_prep diet: wl only for layer 0; wlhi/wllo only layers 1-2 rows j<8
//   (9216 -> 3072 serial 128-MAC loops; the rest zero-filled).

#define N_NODES 50000
#define N_EDGES 200000
#define ETOT    (N_EDGES + N_NODES)
#define HID     128
#define LN_EPS  1e-5f
#define NEG     0.2f
#define NSB     196

typedef __hip_bfloat16 bf16;
typedef __attribute__((ext_vector_type(8))) short v8s;
typedef __attribute__((ext_vector_type(4))) float v4f;
#define MFMA(a, b, c) __builtin_amdgcn_mfma_f32_16x16x32_bf16(a, b, c, 0, 0, 0)

__device__ __forceinline__ float b2f(unsigned short s) {
    return __uint_as_float(((unsigned int)s) << 16);
}
__device__ __forceinline__ unsigned short f2b(float f) {
    __hip_bfloat16 h = __float2bfloat16(f);
    return *reinterpret_cast<unsigned short*>(&h);
}
__device__ __forceinline__ unsigned int pack2(float a, float b) {
    return (unsigned int)f2b(a) | ((unsigned int)f2b(b) << 16);
}
__device__ __forceinline__ float pread(const void* p, size_t i, int isbf) {
    if (isbf) return b2f(((const unsigned short*)p)[i]);
    return ((const float*)p)[i];
}

__global__ void k_fill(float* out, int n, float v) {
    int i = blockIdx.x * blockDim.x + threadIdx.x;
    if (i < n) out[i] = v;
}

// ------------------------------------------------------------ dtype detect
__global__ void k_detect(const unsigned short* __restrict__ xbuf,
                         int* __restrict__ flag) {
    int sane = 0;
    for (int j = threadIdx.x; j < 4096; j += 64) {
        unsigned short v = xbuf[2 * j];
        int e = (v >> 7) & 0xFF;
        if (v == 0 || (e > 96 && e < 160)) sane++;
    }
    for (int off = 32; off > 0; off >>= 1) sane += __shfl_down(sane, off);
    if (threadIdx.x == 0) flag[0] = (sane * 10 >= 4096 * 9) ? 1 : 0;
}

// ------------------------------------------------------------ prep (fused)
struct PrepArgs {
    const void *encw, *encb, *enlg, *enlb, *gatw, *asrc, *adst, *bias,
               *bng, *bnb, *bnm, *bnv, *em1w, *em1b, *emlg, *emlb,
               *em2w, *em2b, *em3w, *em3b;
};
// zeros | pool | w1e(fp32) | gwt | uvt | w2t | wl(L0) | wlt16 mac | wlt16 zero
#define PREP_ITEMS (150000 + 8193 + 1024 + 196608 + 32768 + 8192 + 1024 + 2048 + 2048)
__global__ void k_prep(PrepArgs a, float* __restrict__ pool,
                       unsigned short* __restrict__ gwt,   // [L][c=128][k=512]
                       unsigned short* __restrict__ uvt,   // [n=256][k=128]
                       unsigned short* __restrict__ w2t,   // [n=64][k=128]
                       float* __restrict__ wl,             // [2][4][128] (L0)
                       unsigned short* __restrict__ wlhi,  // [L][16][128]
                       unsigned short* __restrict__ wllo,  // [L][16][128]
                       float* __restrict__ down, int* __restrict__ deg,
                       int* __restrict__ fill, const int* __restrict__ flag) {
    int i = blockIdx.x * 256 + threadIdx.x;
    int bf = flag[0];
    if (i < 150000) {
        int which = i / 50000, idx = i - which * 50000;
        if (which == 0) down[idx] = 0.f;
        else if (which == 1) deg[idx] = 0;
        else fill[idx] = 0;
        return;
    }
    i -= 150000;
    if (i < 8193) {
        const void* s; int off;
        if      (i < 2304) { s = a.encw; off = 0;    }
        else if (i < 2432) { s = a.encb; off = 2304; }
        else if (i < 2560) { s = a.enlg; off = 2432; }
        else if (i < 2688) { s = a.enlb; off = 2560; }
        else if (i < 4224) { s = a.asrc; off = 2688; }
        else if (i < 5760) { s = a.adst; off = 4224; }
        else if (i < 6144) { s = a.bias; off = 5760; }
        else if (i < 6528) { s = a.bng;  off = 6144; }
        else if (i < 6912) { s = a.bnb;  off = 6528; }
        else if (i < 7296) { s = a.bnm;  off = 6912; }
        else if (i < 7680) { s = a.bnv;  off = 7296; }
        else if (i < 7808) { s = a.em1b; off = 7680; }
        else if (i < 7936) { s = a.emlg; off = 7808; }
        else if (i < 8064) { s = a.emlb; off = 7936; }
        else if (i < 8128) { s = a.em2b; off = 8064; }
        else if (i < 8192) { s = a.em3w; off = 8128; }
        else               { s = a.em3b; off = 8192; }
        pool[i] = pread(s, i - off, bf);
        return;
    }
    i -= 8193;
    if (i < 1024) {     // w1e fp32: pool[8200 + k*128+c] = em1_w[256+k][c]
        int k = i >> 7, c = i & 127;
        pool[8200 + i] = pread(a.em1w, (size_t)(256 + k) * 128 + c, bf);
        return;
    }
    i -= 1024;
    if (i < 196608) {   // gwt[L][c][k] = gat_w[L][k&127][(k>>7)*128 + c]
        int L = i >> 16, rem = i & 65535, c = rem >> 9, k = rem & 511;
        gwt[i] = f2b(pread(a.gatw,
            (size_t)L * 65536 + (size_t)(k & 127) * 512 + (k >> 7) * 128 + c, bf));
        return;
    }
    i -= 196608;
    if (i < 32768) {    // uvt[n][k]: n<128 -> em1_w[k][n]; else em1_w[128+k][n-128]
        int n = i >> 7, k = i & 127;
        float v = (n < 128) ? pread(a.em1w, (size_t)k * 128 + n, bf)
                            : pread(a.em1w, (size_t)(128 + k) * 128 + (n - 128), bf);
        uvt[i] = f2b(v);
        return;
    }
    i -= 32768;
    if (i < 8192) {     // w2t[n][k] = em2_w[k][n]
        int n = i >> 7, k = i & 127;
        w2t[i] = f2b(pread(a.em2w, (size_t)k * 64 + n, bf));
        return;
    }
    i -= 8192;
    if (i < 1024) {     // wl layer-0 only: [sd][hh][kk]
        int sd = i >> 9, hh = (i >> 7) & 3, kk = i & 127;
        const void* av = sd ? a.adst : a.asrc;
        float acc = 0.f;
        for (int c = 0; c < 128; c++)
            acc += pread(a.gatw, (size_t)kk * 512 + hh * 128 + c, bf)
                 * pread(av, hh * 128 + c, bf);
        wl[i] = acc;
        return;
    }
    i -= 1024;
    if (i < 2048) {     // wlhi/wllo layers 1-2, rows j<8
        int L = 1 + (i >> 10), rem = i & 1023, j = rem >> 7, kk = rem & 127;
        int sd = j >> 2, hh = j & 3;
        const void* av = sd ? a.adst : a.asrc;
        float d = 0.f;
        for (int c = 0; c < 128; c++)
            d += pread(a.gatw,
                     (size_t)L * 65536 + (size_t)kk * 512 + hh * 128 + c, bf)
               * pread(av, (size_t)L * 512 + hh * 128 + c, bf);
        unsigned short hi = f2b(d);
        wlhi[L * 2048 + j * 128 + kk] = hi;
        wllo[L * 2048 + j * 128 + kk] = f2b(d - b2f(hi));
        return;
    }
    i -= 2048;
    if (i < 2048) {     // zero rows j>=8, layers 1-2
        int L = 1 + (i >> 10), rem = i & 1023, j = 8 + (rem >> 7), kk = rem & 127;
        wlhi[L * 2048 + j * 128 + kk] = 0;
        wllo[L * 2048 + j * 128 + kk] = 0;
    }
}

// ------------------------------------------------------------ graph build
__global__ void k_graph(const int* __restrict__ ei, const int* __restrict__ shock,
                        float* __restrict__ down, int* __restrict__ deg) {
    int e = blockIdx.x * blockDim.x + threadIdx.x;
    if (e < ETOT) {
        int d = (e < N_EDGES) ? ei[N_EDGES + e] : (e - N_EDGES);
        atomicAdd(&deg[d], 1);
        if (e < N_EDGES && shock[ei[e]] != 0) down[d] = 1.f;
    }
}

// ------------------------------------------------------------ scan (2-phase)
__global__ __launch_bounds__(256) void k_scan1(
        const int* __restrict__ deg, int* __restrict__ bsum) {
    __shared__ int red[4];
    int b = blockIdx.x, t = threadIdx.x, lane = t & 63, w = t >> 6;
    int idx = b * 256 + t;
    int v = (idx < N_NODES) ? deg[idx] : 0;
#pragma unroll
    for (int off = 1; off < 64; off <<= 1) v += __shfl_xor(v, off);
    if (lane == 0) red[w] = v;
    __syncthreads();
    if (t == 0) bsum[b] = red[0] + red[1] + red[2] + red[3];
}

__global__ __launch_bounds__(256) void k_scan2(
        const int* __restrict__ deg, const int* __restrict__ bsum,
        int* __restrict__ row_start) {
    __shared__ int red[4];
    __shared__ int wsum[4];
    int b = blockIdx.x, t = threadIdx.x, lane = t & 63, w = t >> 6;
    int pv = (t < b) ? bsum[t] : 0;
    int sm = pv;
#pragma unroll
    for (int off = 1; off < 64; off <<= 1) sm += __shfl_xor(sm, off);
    if (lane == 0) red[w] = sm;
    int idx = b * 256 + t;
    int v = (idx < N_NODES) ? deg[idx] : 0;
    int inc = v;
#pragma unroll
    for (int off = 1; off < 64; off <<= 1) {
        int u = __shfl_up(inc, off);
        if (lane >= off) inc += u;
    }
    if (lane == 63) wsum[w] = inc;
    __syncthreads();
    int boff = red[0] + red[1] + red[2] + red[3];
    int wo = 0;
#pragma unroll
    for (int i = 0; i < 4; i++) if (i < w) wo += wsum[i];
    if (idx < N_NODES) row_start[idx] = boff + wo + (inc - v);
    if (b == 0 && t == 0) row_start[N_NODES] = ETOT;
}

__global__ void k_csr(const int* __restrict__ ei, const int* __restrict__ row_start,
                      int* __restrict__ fill, int* __restrict__ csr_src) {
    int e = blockIdx.x * blockDim.x + threadIdx.x;
    if (e < ETOT) {
        int s, d;
        if (e < N_EDGES) { s = ei[e]; d = ei[N_EDGES + e]; }
        else             { s = e - N_EDGES; d = s; }
        int pos = row_start[d] + atomicAdd(&fill[d], 1);
        csr_src[pos] = s;
    }
}

// ------------------------------------------------------------ encoder -> h bf16
__global__ __launch_bounds__(256) void k_encoder(
        const void* __restrict__ xraw, const int* __restrict__ flag,
        const int* __restrict__ shock, const float* __restrict__ down,
        const float* __restrict__ enc_w, const float* __restrict__ enc_b,
        const float* __restrict__ ln_g, const float* __restrict__ ln_b,
        unsigned short* __restrict__ h) {
    __shared__ float sw[2304];
    __shared__ float sp[384];
    int t = threadIdx.x;
    for (int i = t; i < 2304; i += 256) sw[i] = enc_w[i];
    if (t < 128)      sp[t] = enc_b[t];
    else if (t < 256) sp[t] = ln_g[t - 128];
    if (t < 128)      sp[256 + t] = ln_b[t];
    __syncthreads();

    int w = t >> 6, l = t & 63;
    int n = blockIdx.x * 4 + w;
    int bf = flag[0];
    int c0 = 2 * l, c1 = c0 + 1;

    float xv = (l < 16) ? pread(xraw, (size_t)n * 16 + l, bf) : 0.f;
    float xs = (float)shock[n];
    float xd = down[n];

    float a0 = sp[c0], a1 = sp[c1];
#pragma unroll
    for (int k = 0; k < 16; k++) {
        float xk = __shfl(xv, k);
        a0 = fmaf(xk, sw[k * HID + c0], a0);
        a1 = fmaf(xk, sw[k * HID + c1], a1);
    }
    a0 = fmaf(xs, sw[16 * HID + c0], a0); a1 = fmaf(xs, sw[16 * HID + c1], a1);
    a0 = fmaf(xd, sw[17 * HID + c0], a0); a1 = fmaf(xd, sw[17 * HID + c1], a1);

    float s = a0 + a1, q = a0 * a0 + a1 * a1;
#pragma unroll
    for (int off = 1; off < 64; off <<= 1) {
        s += __shfl_xor(s, off);
        q += __shfl_xor(q, off);
    }
    float mu = s * (1.f / 128.f);
    float var = q * (1.f / 128.f) - mu * mu;
    float rstd = rsqrtf(var + LN_EPS);
    float v0 = fmaxf((a0 - mu) * rstd * sp[128 + c0] + sp[256 + c0], 0.f);
    float v1 = fmaxf((a1 - mu) * rstd * sp[128 + c1] + sp[256 + c1], 0.f);
    *(unsigned int*)&h[(size_t)n * HID + c0] = pack2(v0, v1);
}

// ------------------------------------------------------------ attention logits
// al_s[n,h] = h[n,:] . wl[0][h][:], al_d[n,h] = h[n,:] . wl[1][h][:]
// 16 lanes per node (4 nodes/wave, 16 nodes/block).
__global__ __launch_bounds__(256) void k_logits(
        const unsigned short* __restrict__ h, const float* __restrict__ wl,
        float* __restrict__ al_s, float* __restrict__ al_d) {
    __shared__ float wls[1024];
    int t = threadIdx.x;
    for (int i = t; i < 1024; i += 256) wls[i] = wl[i];
    __syncthreads();
    int lane = t & 63, w = t >> 6, l15 = lane & 15, q = lane >> 4;
    int n = blockIdx.x * 16 + w * 4 + q;
    v8s hv = *(const v8s*)&h[(size_t)n * 128 + l15 * 8];
    float hf[8];
#pragma unroll
    for (int m = 0; m < 8; m++) hf[m] = b2f((unsigned short)hv[m]);
    float p[8] = {};
#pragma unroll
    for (int j = 0; j < 8; j++) {
        float4 wa = *(const float4*)&wls[j * 128 + l15 * 8];
        float4 wb = *(const float4*)&wls[j * 128 + l15 * 8 + 4];
        p[j] = fmaf(hf[0], wa.x, p[j]); p[j] = fmaf(hf[1], wa.y, p[j]);
        p[j] = fmaf(hf[2], wa.z, p[j]); p[j] = fmaf(hf[3], wa.w, p[j]);
        p[j] = fmaf(hf[4], wb.x, p[j]); p[j] = fmaf(hf[5], wb.y, p[j]);
        p[j] = fmaf(hf[6], wb.z, p[j]); p[j] = fmaf(hf[7], wb.w, p[j]);
    }
#pragma unroll
    for (int off = 1; off < 16; off <<= 1)
#pragma unroll
        for (int j = 0; j < 8; j++) p[j] += __shfl_xor(p[j], off);
    if (l15 == 0) {
        float4 vs = {p[0], p[1], p[2], p[3]};
        float4 vd = {p[4], p[5], p[6], p[7]};
        *(float4*)&al_s[n * 4] = vs;
        *(float4*)&al_d[n * 4] = vd;
    }
}

// ------------------------------------------------------------ aggregation v4
// wave per node, 4 edges per iteration: 16-lane group g handles edge slot g
// (lane covers 8 channels); cross-group shfl reduce at the end.
__global__ __launch_bounds__(256) void k_agg4(
        const unsigned short* __restrict__ h, const float* __restrict__ al_src,
        const float* __restrict__ al_dst,
        const int* __restrict__ row_start, const int* __restrict__ csr_src,
        unsigned short* __restrict__ agg) {
    int w = threadIdx.x >> 6, l = threadIdx.x & 63;
    int n = blockIdx.x * 4 + w;
    int g = l >> 4, c = l & 15;
    int r0 = row_start[n], r1 = row_start[n + 1];
    int last = r1 - 1;
    int iters = (r1 - r0 + 3) >> 2;
    float4 ad4 = *(const float4*)&al_dst[n * 4];
    float s0 = 0.f, s1 = 0.f, s2 = 0.f, s3 = 0.f;
    float acc[4][8] = {};

    int j0 = r0 + g;
    int vC = (j0 <= last) ? 1 : 0;
    int jc = vC ? j0 : last;
    int iC = csr_src[jc];
    float4 aC = *(const float4*)&al_src[iC * 4];
    v8s hC = *(const v8s*)&h[(size_t)iC * 128 + c * 8];

#pragma unroll 1
    for (int it = 0; it < iters; it++) {
        float4 aN = aC; v8s hN = hC; int vN = 0;
        if (it + 1 < iters) {                       // wave-uniform branch
            int jn = r0 + (it + 1) * 4 + g;
            vN = (jn <= last) ? 1 : 0;
            jn = vN ? jn : last;
            int iN = csr_src[jn];
            aN = *(const float4*)&al_src[iN * 4];
            hN = *(const v8s*)&h[(size_t)iN * 128 + c * 8];
        }
        float t0 = aC.x + ad4.x; t0 = (t0 >= 0.f) ? t0 : NEG * t0;
        float t1 = aC.y + ad4.y; t1 = (t1 >= 0.f) ? t1 : NEG * t1;
        float t2 = aC.z + ad4.z; t2 = (t2 >= 0.f) ? t2 : NEG * t2;
        float t3 = aC.w + ad4.w; t3 = (t3 >= 0.f) ? t3 : NEG * t3;
        float m = (float)vC;
        float e0 = __expf(t0) * m, e1 = __expf(t1) * m,
              e2 = __expf(t2) * m, e3 = __expf(t3) * m;
        s0 += e0; s1 += e1; s2 += e2; s3 += e3;
#pragma unroll
        for (int i = 0; i < 8; i++) {
            float hv = b2f((unsigned short)hC[i]);
            acc[0][i] = fmaf(e0, hv, acc[0][i]);
            acc[1][i] = fmaf(e1, hv, acc[1][i]);
            acc[2][i] = fmaf(e2, hv, acc[2][i]);
            acc[3][i] = fmaf(e3, hv, acc[3][i]);
        }
        aC = aN; hC = hN; vC = vN;
    }
    s0 += __shfl_xor(s0, 16); s0 += __shfl_xor(s0, 32);
    s1 += __shfl_xor(s1, 16); s1 += __shfl_xor(s1, 32);
    s2 += __shfl_xor(s2, 16); s2 += __shfl_xor(s2, 32);
    s3 += __shfl_xor(s3, 16); s3 += __shfl_xor(s3, 32);
#pragma unroll
    for (int hh = 0; hh < 4; hh++)
#pragma unroll
        for (int i = 0; i < 8; i++) {
            acc[hh][i] += __shfl_xor(acc[hh][i], 16);
            acc[hh][i] += __shfl_xor(acc[hh][i], 32);
        }
    float sg = (g == 0) ? s0 : (g == 1) ? s1 : (g == 2) ? s2 : s3;
    float inv = 1.f / (sg + 1e-16f);
    short o[8];
#pragma unroll
    for (int i = 0; i < 8; i++) {
        float av = (g == 0) ? acc[0][i] : (g == 1) ? acc[1][i]
                 : (g == 2) ? acc[2][i] : acc[3][i];
        o[i] = (short)f2b(av * inv);
    }
    *(v8s*)&agg[(size_t)n * 512 + g * 128 + c * 8] = *(const v8s*)o;
}

// ------------------------------------------------------------ K=512 GEMM + BN
// h' = relu?(BN(0.25*(agg @ W_stacked) + bias)); Wt layout [c=128][k=512].
// Double-buffered LDS (1 barrier/chunk) + fused next-layer logits via
// skinny MFMA with bf16 hi+lo wl (precision ~ fp32).
__global__ __launch_bounds__(256, 4) void k_gemm2(
        const unsigned short* __restrict__ A,     // agg [N][512]
        const unsigned short* __restrict__ Wt,    // [128][512]
        const float* __restrict__ bias,
        const float* __restrict__ bn_g, const float* __restrict__ bn_b,
        const float* __restrict__ bn_m, const float* __restrict__ bn_v,
        unsigned short* __restrict__ hout, int relu_flag,
        const unsigned short* __restrict__ wlhi,  // [16][128]
        const unsigned short* __restrict__ wllo,  // [16][128]
        float* __restrict__ al_s, float* __restrict__ al_d, int logit_flag) {
    __shared__ __align__(16) unsigned short As[2][64 * 136];
    int t = threadIdx.x;
    int lane = t & 63, w = t >> 6, l15 = lane & 15, q = lane >> 4;
    int m0 = blockIdx.x * 64;
    int c0 = w * 32 + 2 * l15, c1 = c0 + 1;

    v8s st[4];
#pragma unroll
    for (int it = 0; it < 4; it++) {
        int cc = t + it * 256, row = cc >> 4, ch = cc & 15;
        v8s val = {0, 0, 0, 0, 0, 0, 0, 0};
        if (m0 + row < N_NODES)
            val = *(const v8s*)&A[(size_t)(m0 + row) * 512 + ch * 8];
        st[it] = val;
    }
#pragma unroll
    for (int it = 0; it < 4; it++) {
        int cc = t + it * 256, row = cc >> 4, ch = cc & 15;
        *(v8s*)&As[0][row * 136 + ch * 8] = st[it];
    }
    __syncthreads();

    v4f acc[4][2] = {};
#pragma unroll
    for (int kc = 0; kc < 4; kc++) {
        if (kc < 3) {
#pragma unroll
            for (int it = 0; it < 4; it++) {
                int cc = t + it * 256, row = cc >> 4, ch = cc & 15;
                v8s val = {0, 0, 0, 0, 0, 0, 0, 0};
                if (m0 + row < N_NODES)
                    val = *(const v8s*)&A[(size_t)(m0 + row) * 512
                                          + (kc + 1) * 128 + ch * 8];
                st[it] = val;
            }
        }
#pragma unroll
        for (int kt = 0; kt < 4; kt++) {
            v8s b0 = *(const v8s*)&Wt[(size_t)c0 * 512 + kc * 128 + kt * 32 + q * 8];
            v8s b1 = *(const v8s*)&Wt[(size_t)c1 * 512 + kc * 128 + kt * 32 + q * 8];
#pragma unroll
            for (int mt = 0; mt < 4; mt++) {
                v8s a = *(const v8s*)&As[kc & 1][(mt * 16 + l15) * 136
                                                 + kt * 32 + q * 8];
                acc[mt][0] = MFMA(a, b0, acc[mt][0]);
                acc[mt][1] = MFMA(a, b1, acc[mt][1]);
            }
        }
        if (kc < 3) {
#pragma unroll
            for (int it = 0; it < 4; it++) {
                int cc = t + it * 256, row = cc >> 4, ch = cc & 15;
                *(v8s*)&As[(kc + 1) & 1][row * 136 + ch * 8] = st[it];
            }
        }
        __syncthreads();
    }

    float bi0 = bias[c0], bi1 = bias[c1];
    float sc0 = rsqrtf(bn_v[c0] + LN_EPS) * bn_g[c0];
    float sc1 = rsqrtf(bn_v[c1] + LN_EPS) * bn_g[c1];
    float sh0 = bn_b[c0] - bn_m[c0] * sc0;
    float sh1 = bn_b[c1] - bn_m[c1] * sc1;
#pragma unroll
    for (int mt = 0; mt < 4; mt++)
#pragma unroll
        for (int r = 0; r < 4; r++) {
            int row = mt * 16 + q * 4 + r;
            int node = m0 + row;
            float v0 = (0.25f * acc[mt][0][r] + bi0) * sc0 + sh0;
            float v1 = (0.25f * acc[mt][1][r] + bi1) * sc1 + sh1;
            if (relu_flag) { v0 = fmaxf(v0, 0.f); v1 = fmaxf(v1, 0.f); }
            unsigned int pv = pack2(v0, v1);
            if (node < N_NODES)
                *(unsigned int*)&hout[(size_t)node * 128 + c0] = pv;
            if (logit_flag)
                *(unsigned int*)&As[0][row * 136 + c0] = pv;
        }

    if (logit_flag) {
        __syncthreads();
        v4f accL = {0.f, 0.f, 0.f, 0.f};
#pragma unroll
        for (int kt = 0; kt < 4; kt++) {
            v8s a  = *(const v8s*)&As[0][(w * 16 + l15) * 136 + kt * 32 + q * 8];
            v8s bh = *(const v8s*)&wlhi[(size_t)l15 * 128 + kt * 32 + q * 8];
            v8s bl = *(const v8s*)&wllo[(size_t)l15 * 128 + kt * 32 + q * 8];
            accL = MFMA(a, bh, accL);
            accL = MFMA(a, bl, accL);
        }
        if (l15 < 8) {
#pragma unroll
            for (int r = 0; r < 4; r++) {
                int node = m0 + w * 16 + q * 4 + r;
                if (node < N_NODES) {
                    if (l15 < 4) al_s[node * 4 + l15] = accL[r];
                    else         al_d[node * 4 + (l15 - 4)] = accL[r];
                }
            }
        }
    }
}

// ------------------------------------------------------------ UV GEMM
__global__ __launch_bounds__(256, 4) void k_uvgemm(
        const unsigned short* __restrict__ A, const unsigned short* __restrict__ Wt,
        unsigned short* __restrict__ UV) {
    __shared__ __align__(16) unsigned short As[64 * 136];
    int t = threadIdx.x;
    int lane = t & 63, w = t >> 6, l15 = lane & 15, q = lane >> 4;
    int m0 = blockIdx.x * 64, n0 = blockIdx.y * 128;
    int c0 = n0 + w * 32 + 2 * l15;

    v8s b[2][4];
#pragma unroll
    for (int nt = 0; nt < 2; nt++)
#pragma unroll
        for (int kt = 0; kt < 4; kt++)
            b[nt][kt] = *(const v8s*)&Wt[(size_t)(c0 + nt) * 128 + kt * 32 + q * 8];
#pragma unroll
    for (int it = 0; it < 4; it++) {
        int c = t + it * 256;
        int row = c >> 4, ch = c & 15;
        v8s val = {0, 0, 0, 0, 0, 0, 0, 0};
        if (m0 + row < N_NODES)
            val = *(const v8s*)&A[(size_t)(m0 + row) * 128 + ch * 8];
        *(v8s*)&As[row * 136 + ch * 8] = val;
    }
    __syncthreads();

    v4f acc[4][2] = {};
#pragma unroll
    for (int kt = 0; kt < 4; kt++)
#pragma unroll
        for (int mt = 0; mt < 4; mt++) {
            v8s a = *(const v8s*)&As[(mt * 16 + l15) * 136 + kt * 32 + q * 8];
            acc[mt][0] = MFMA(a, b[0][kt], acc[mt][0]);
            acc[mt][1] = MFMA(a, b[1][kt], acc[mt][1]);
        }
#pragma unroll
    for (int mt = 0; mt < 4; mt++)
#pragma unroll
        for (int r = 0; r < 4; r++) {
            int node = m0 + mt * 16 + q * 4 + r;
            if (node < N_NODES)
                *(unsigned int*)&UV[(size_t)node * 256 + c0] =
                    pack2(acc[mt][0][r], acc[mt][1][r]);
        }
}

// ------------------------------------------------------------ edge MLP v4
// One edge per 16-lane group, 16 edges per block, no serial edge loop.
__global__ __launch_bounds__(256) void k_edgemlp4(
        const unsigned short* __restrict__ UV, const int* __restrict__ ei,
        const void* __restrict__ eraw, const int* __restrict__ flag,
        const float* __restrict__ w1e, const float* __restrict__ em1b,
        const float* __restrict__ lng, const float* __restrict__ lnb,
        const unsigned short* __restrict__ w2t, const float* __restrict__ em2b,
        const float* __restrict__ em3w, const float* __restrict__ em3b,
        float* __restrict__ out) {
    __shared__ __align__(16) unsigned short za[16 * 136];   // 4352 B
    __shared__ __align__(16) float w1e_s[1024];             // 4096 B
    __shared__ __align__(16) unsigned short ea_s[16 * 8];   // 256 B
    __shared__ int idx_s[32];
    __shared__ float part[4][16];

    int t = threadIdx.x;
    int lane = t & 63, w = t >> 6, l15 = lane & 15, q = lane >> 4;
    int g = t >> 4;            // edge group 0..15
    int e0 = blockIdx.x * 16;
    int bf = flag[0];
    int cb = l15 * 8;          // this lane's 8 channels

    for (int i = t; i < 1024; i += 256) w1e_s[i] = w1e[i];
    if (t < 16) {
        idx_s[t * 2]     = ei[e0 + t];
        idx_s[t * 2 + 1] = ei[N_EDGES + e0 + t];
        if (bf) {
            *(v8s*)&ea_s[t * 8] =
                *(const v8s*)((const unsigned short*)eraw + (size_t)(e0 + t) * 8);
        } else {
            short tmp[8];
#pragma unroll
            for (int j = 0; j < 8; j++)
                tmp[j] = (short)f2b(((const float*)eraw)[(size_t)(e0 + t) * 8 + j]);
            *(v8s*)&ea_s[t * 8] = *(const v8s*)tmp;
        }
    }
    __syncthreads();

    {
        int src = idx_s[g * 2], dst = idx_s[g * 2 + 1];
        v8s uu = *(const v8s*)&UV[(size_t)src * 256 + cb];
        v8s vv = *(const v8s*)&UV[(size_t)dst * 256 + 128 + cb];
        v8s ea8 = *(const v8s*)&ea_s[g * 8];

        float bc[8], lg[8], lb[8];
#pragma unroll
        for (int j = 0; j < 8; j++) {
            bc[j] = em1b[cb + j];
            lg[j] = lng[cb + j];
            lb[j] = lnb[cb + j];
        }
        float eaf[8];
#pragma unroll
        for (int k = 0; k < 8; k++) eaf[k] = b2f((unsigned short)ea8[k]);
        float e[8] = {};
#pragma unroll
        for (int k = 0; k < 8; k++) {
            float4 wa = *(const float4*)&w1e_s[k * 128 + cb];
            float4 wb = *(const float4*)&w1e_s[k * 128 + cb + 4];
            e[0] = fmaf(eaf[k], wa.x, e[0]);
            e[1] = fmaf(eaf[k], wa.y, e[1]);
            e[2] = fmaf(eaf[k], wa.z, e[2]);
            e[3] = fmaf(eaf[k], wa.w, e[3]);
            e[4] = fmaf(eaf[k], wb.x, e[4]);
            e[5] = fmaf(eaf[k], wb.y, e[5]);
            e[6] = fmaf(eaf[k], wb.z, e[6]);
            e[7] = fmaf(eaf[k], wb.w, e[7]);
        }
        float z[8];
        float s = 0.f, qq = 0.f;
#pragma unroll
        for (int j = 0; j < 8; j++) {
            float zz = b2f((unsigned short)uu[j]) + b2f((unsigned short)vv[j])
                     + e[j] + bc[j];
            z[j] = zz;
            s += zz;
            qq = fmaf(zz, zz, qq);
        }
#pragma unroll
        for (int off = 1; off < 16; off <<= 1) {
            s  += __shfl_xor(s, off);
            qq += __shfl_xor(qq, off);
        }
        float mu = s * (1.f / 128.f);
        float var = qq * (1.f / 128.f) - mu * mu;
        float rstd = rsqrtf(var + LN_EPS);
        short o[8];
#pragma unroll
        for (int j = 0; j < 8; j++)
            o[j] = (short)f2b(fmaxf((z[j] - mu) * rstd * lg[j] + lb[j], 0.f));
        *(v8s*)&za[g * 136 + cb] = *(const v8s*)o;
    }
    __syncthreads();

    // layer 2 MFMA: wave w -> cols w*16..+15 over 16 edge rows
    v8s b2v[4];
#pragma unroll
    for (int kt = 0; kt < 4; kt++)
        b2v[kt] = *(const v8s*)&w2t[(size_t)(w * 16 + l15) * 128 + kt * 32 + q * 8];
    v4f acc2 = {0.f, 0.f, 0.f, 0.f};
#pragma unroll
    for (int kt = 0; kt < 4; kt++) {
        v8s a = *(const v8s*)&za[l15 * 136 + kt * 32 + q * 8];
        acc2 = MFMA(a, b2v[kt], acc2);
    }

    {
        int col = w * 16 + l15;
        float b2c = em2b[col], w3c = em3w[col];
#pragma unroll
        for (int r = 0; r < 4; r++) {
            float vv2 = fmaxf(acc2[r] + b2c, 0.f) * w3c;
#pragma unroll
            for (int off = 1; off < 16; off <<= 1) vv2 += __shfl_xor(vv2, off);
            if (l15 == 0) part[w][q * 4 + r] = vv2;
        }
    }
    __syncthreads();
    if (t < 16)
        out[e0 + t] = part[0][t] + part[1][t] + part[2][t] + part[3][t]
                    + em3b[0];
}

// ------------------------------------------------------------ launch
extern "C" __attribute__((visibility("default")))
void kernel_launch(void* const* d_in, const int* in_sizes, int n_in,
                   void* d_out, int out_size, void* d_ws, size_t ws_size,
                   hipStream_t stream) {
    float* out = (float*)d_out;

    static const int EXP_SIZES[24] = {
        800000, 400000, 1600000, 50000, 2304, 128, 128, 128,
        196608, 1536, 1536, 384, 384, 384, 384, 384,
        33792, 128, 128, 128, 8192, 64, 64, 1};
    bool ok = (n_in == 24) && (out_size == N_EDGES);
    if (ok) for (int i = 0; i < 24; i++) ok = ok && (in_sizes[i] == EXP_SIZES[i]);
    if (!ok) {
        k_fill<<<(out_size + 255) / 256, 256, 0, stream>>>(out, out_size, 4.0f);
        return;
    }
    if (ws_size < (size_t)68000000) {
        k_fill<<<(out_size + 255) / 256, 256, 0, stream>>>(out, out_size, 8.0f);
        return;
    }

    const int* ei    = (const int*)d_in[1];
    const int* shock = (const int*)d_in[3];

    char* ws = (char*)d_ws;
    unsigned short* h_bf  = (unsigned short*)(ws + 0);          // 12,800,000
    unsigned short* agg   = (unsigned short*)(ws + 12800000);   // 51,200,000
    unsigned short* UV    = agg;  // aliases agg (agg dead before k_uvgemm)
    float* al_s    = (float*)(ws + 64000000);
    float* al_d    = (float*)(ws + 64800000);
    float* down    = (float*)(ws + 65600000);
    int*   deg     = (int*)  (ws + 65800000);
    int*   row_st  = (int*)  (ws + 66000000);
    int*   fill    = (int*)  (ws + 66200064);
    int*   csr_src = (int*)  (ws + 66400064);
    int*   flag    = (int*)  (ws + 67400064);
    unsigned short* gwt = (unsigned short*)(ws + 67400128);     // 393,216
    unsigned short* uvt = (unsigned short*)(ws + 67793344);     // 65,536
    unsigned short* w2t = (unsigned short*)(ws + 67858880);     // 16,384
    float* pool    = (float*)(ws + 67875264);                   // 9,224 f32
    int*   bsum    = (int*)  (ws + 67912160);                   // 784 B
    float* wl      = (float*)(ws + 67912960);                   // 12,288 B
    unsigned short* wlhi = (unsigned short*)(ws + 67925248);    // 12,288 B
    unsigned short* wllo = (unsigned short*)(ws + 67937536);    // 12,288 B

    float* cencw = pool + 0;    float* cencb = pool + 2304;
    float* cenlg = pool + 2432; float* cenlb = pool + 2560;
    float* cbias = pool + 5760; float* cbng  = pool + 6144;
    float* cbnb  = pool + 6528; float* cbnm  = pool + 6912;
    float* cbnv  = pool + 7296; float* cem1b = pool + 7680;
    float* cemlg = pool + 7808; float* cemlb = pool + 7936;
    float* cem2b = pool + 8064; float* cem3w = pool + 8128;
    float* cem3b = pool + 8192;
    float* w1e   = pool + 8200;   // [8][128] fp32

    k_detect<<<1, 64, 0, stream>>>((const unsigned short*)d_in[0], flag);

    PrepArgs pa;
    pa.encw = d_in[4];  pa.encb = d_in[5];  pa.enlg = d_in[6];  pa.enlb = d_in[7];
    pa.gatw = d_in[8];  pa.asrc = d_in[9];  pa.adst = d_in[10]; pa.bias = d_in[11];
    pa.bng  = d_in[12]; pa.bnb  = d_in[13]; pa.bnm  = d_in[14]; pa.bnv  = d_in[15];
    pa.em1w = d_in[16]; pa.em1b = d_in[17]; pa.emlg = d_in[18]; pa.emlb = d_in[19];
    pa.em2w = d_in[20]; pa.em2b = d_in[21]; pa.em3w = d_in[22]; pa.em3b = d_in[23];
    k_prep<<<(PREP_ITEMS + 255) / 256, 256, 0, stream>>>(
        pa, pool, gwt, uvt, w2t, wl, wlhi, wllo, down, deg, fill, flag);

    k_graph<<<(ETOT + 255) / 256, 256, 0, stream>>>(ei, shock, down, deg);
    k_scan1<<<NSB, 256, 0, stream>>>(deg, bsum);
    k_scan2<<<NSB, 256, 0, stream>>>(deg, bsum, row_st);
    k_csr<<<(ETOT + 255) / 256, 256, 0, stream>>>(ei, row_st, fill, csr_src);
    k_encoder<<<N_NODES / 4, 256, 0, stream>>>(
        d_in[0], flag, shock, down, cencw, cencb, cenlg, cenlb, h_bf);
    k_logits<<<N_NODES / 16, 256, 0, stream>>>(h_bf, wl, al_s, al_d);
    for (int i = 0; i < 3; i++) {
        k_agg4<<<N_NODES / 4, 256, 0, stream>>>(
            h_bf, al_s, al_d, row_st, csr_src, agg);
        k_gemm2<<<782, 256, 0, stream>>>(
            agg, gwt + (size_t)i * 65536,
            cbias + i * 128, cbng + i * 128, cbnb + i * 128,
            cbnm + i * 128, cbnv + i * 128, h_bf, (i < 2) ? 1 : 0,
            wlhi + (size_t)(i + 1) * 2048, wllo + (size_t)(i + 1) * 2048,
            al_s, al_d, (i < 2) ? 1 : 0);
    }
    k_uvgemm<<<dim3(782, 2), 256, 0, stream>>>(h_bf, uvt, UV);
    k_edgemlp4<<<N_EDGES / 16, 256, 0, stream>>>(
        UV, ei, d_in[2], flag, w1e, cem1b, cemlg, cemlb,
        w2t, cem2b, cem3w, cem3b, out);
}

// Round 5
// 476.364 us; speedup vs baseline: 1.0086x; 1.0086x over previous
//
#include <hip/hip_runtime.h>
#include <hip/hip_bf16.h>

// ShockPropagationGNN — round 18 (base: round 17, 480us; best 465us r13).
// - k_edgemlp5: 512 threads/block, 64 edges/block (grid 3125), 2 edges per
//   16-lane group. Keeps v3's per-block amortization (w1e/w2t/params) while
//   halving the serial UV-gather chain (v4 lesson: overhead ×4 beat the
//   latency win; v5 keeps overhead ≈ v3, chain 4->2).
//   Layer-2 MFMA split over 8 waves: wave w = col block (w&3), row half (w>>2).

#define N_NODES 50000
#define N_EDGES 200000
#define ETOT    (N_EDGES + N_NODES)
#define HID     128
#define LN_EPS  1e-5f
#define NEG     0.2f
#define NSB     196

typedef __hip_bfloat16 bf16;
typedef __attribute__((ext_vector_type(8))) short v8s;
typedef __attribute__((ext_vector_type(4))) float v4f;
#define MFMA(a, b, c) __builtin_amdgcn_mfma_f32_16x16x32_bf16(a, b, c, 0, 0, 0)

__device__ __forceinline__ float b2f(unsigned short s) {
    return __uint_as_float(((unsigned int)s) << 16);
}
__device__ __forceinline__ unsigned short f2b(float f) {
    __hip_bfloat16 h = __float2bfloat16(f);
    return *reinterpret_cast<unsigned short*>(&h);
}
__device__ __forceinline__ unsigned int pack2(float a, float b) {
    return (unsigned int)f2b(a) | ((unsigned int)f2b(b) << 16);
}
__device__ __forceinline__ float pread(const void* p, size_t i, int isbf) {
    if (isbf) return b2f(((const unsigned short*)p)[i]);
    return ((const float*)p)[i];
}

__global__ void k_fill(float* out, int n, float v) {
    int i = blockIdx.x * blockDim.x + threadIdx.x;
    if (i < n) out[i] = v;
}

// ------------------------------------------------------------ dtype detect
__global__ void k_detect(const unsigned short* __restrict__ xbuf,
                         int* __restrict__ flag) {
    int sane = 0;
    for (int j = threadIdx.x; j < 4096; j += 64) {
        unsigned short v = xbuf[2 * j];
        int e = (v >> 7) & 0xFF;
        if (v == 0 || (e > 96 && e < 160)) sane++;
    }
    for (int off = 32; off > 0; off >>= 1) sane += __shfl_down(sane, off);
    if (threadIdx.x == 0) flag[0] = (sane * 10 >= 4096 * 9) ? 1 : 0;
}

// ------------------------------------------------------------ prep (fused)
struct PrepArgs {
    const void *encw, *encb, *enlg, *enlb, *gatw, *asrc, *adst, *bias,
               *bng, *bnb, *bnm, *bnv, *em1w, *em1b, *emlg, *emlb,
               *em2w, *em2b, *em3w, *em3b;
};
// zeros | pool | w1e(fp32) | gwt | uvt | w2t | wl(L0) | wlt16 mac | wlt16 zero
#define PREP_ITEMS (150000 + 8193 + 1024 + 196608 + 32768 + 8192 + 1024 + 2048 + 2048)
__global__ void k_prep(PrepArgs a, float* __restrict__ pool,
                       unsigned short* __restrict__ gwt,   // [L][c=128][k=512]
                       unsigned short* __restrict__ uvt,   // [n=256][k=128]
                       unsigned short* __restrict__ w2t,   // [n=64][k=128]
                       float* __restrict__ wl,             // [2][4][128] (L0)
                       unsigned short* __restrict__ wlhi,  // [L][16][128]
                       unsigned short* __restrict__ wllo,  // [L][16][128]
                       float* __restrict__ down, int* __restrict__ deg,
                       int* __restrict__ fill, const int* __restrict__ flag) {
    int i = blockIdx.x * 256 + threadIdx.x;
    int bf = flag[0];
    if (i < 150000) {
        int which = i / 50000, idx = i - which * 50000;
        if (which == 0) down[idx] = 0.f;
        else if (which == 1) deg[idx] = 0;
        else fill[idx] = 0;
        return;
    }
    i -= 150000;
    if (i < 8193) {
        const void* s; int off;
        if      (i < 2304) { s = a.encw; off = 0;    }
        else if (i < 2432) { s = a.encb; off = 2304; }
        else if (i < 2560) { s = a.enlg; off = 2432; }
        else if (i < 2688) { s = a.enlb; off = 2560; }
        else if (i < 4224) { s = a.asrc; off = 2688; }
        else if (i < 5760) { s = a.adst; off = 4224; }
        else if (i < 6144) { s = a.bias; off = 5760; }
        else if (i < 6528) { s = a.bng;  off = 6144; }
        else if (i < 6912) { s = a.bnb;  off = 6528; }
        else if (i < 7296) { s = a.bnm;  off = 6912; }
        else if (i < 7680) { s = a.bnv;  off = 7296; }
        else if (i < 7808) { s = a.em1b; off = 7680; }
        else if (i < 7936) { s = a.emlg; off = 7808; }
        else if (i < 8064) { s = a.emlb; off = 7936; }
        else if (i < 8128) { s = a.em2b; off = 8064; }
        else if (i < 8192) { s = a.em3w; off = 8128; }
        else               { s = a.em3b; off = 8192; }
        pool[i] = pread(s, i - off, bf);
        return;
    }
    i -= 8193;
    if (i < 1024) {     // w1e fp32: pool[8200 + k*128+c] = em1_w[256+k][c]
        int k = i >> 7, c = i & 127;
        pool[8200 + i] = pread(a.em1w, (size_t)(256 + k) * 128 + c, bf);
        return;
    }
    i -= 1024;
    if (i < 196608) {   // gwt[L][c][k] = gat_w[L][k&127][(k>>7)*128 + c]
        int L = i >> 16, rem = i & 65535, c = rem >> 9, k = rem & 511;
        gwt[i] = f2b(pread(a.gatw,
            (size_t)L * 65536 + (size_t)(k & 127) * 512 + (k >> 7) * 128 + c, bf));
        return;
    }
    i -= 196608;
    if (i < 32768) {    // uvt[n][k]: n<128 -> em1_w[k][n]; else em1_w[128+k][n-128]
        int n = i >> 7, k = i & 127;
        float v = (n < 128) ? pread(a.em1w, (size_t)k * 128 + n, bf)
                            : pread(a.em1w, (size_t)(128 + k) * 128 + (n - 128), bf);
        uvt[i] = f2b(v);
        return;
    }
    i -= 32768;
    if (i < 8192) {     // w2t[n][k] = em2_w[k][n]
        int n = i >> 7, k = i & 127;
        w2t[i] = f2b(pread(a.em2w, (size_t)k * 64 + n, bf));
        return;
    }
    i -= 8192;
    if (i < 1024) {     // wl layer-0 only: [sd][hh][kk]
        int sd = i >> 9, hh = (i >> 7) & 3, kk = i & 127;
        const void* av = sd ? a.adst : a.asrc;
        float acc = 0.f;
        for (int c = 0; c < 128; c++)
            acc += pread(a.gatw, (size_t)kk * 512 + hh * 128 + c, bf)
                 * pread(av, hh * 128 + c, bf);
        wl[i] = acc;
        return;
    }
    i -= 1024;
    if (i < 2048) {     // wlhi/wllo layers 1-2, rows j<8
        int L = 1 + (i >> 10), rem = i & 1023, j = rem >> 7, kk = rem & 127;
        int sd = j >> 2, hh = j & 3;
        const void* av = sd ? a.adst : a.asrc;
        float d = 0.f;
        for (int c = 0; c < 128; c++)
            d += pread(a.gatw,
                     (size_t)L * 65536 + (size_t)kk * 512 + hh * 128 + c, bf)
               * pread(av, (size_t)L * 512 + hh * 128 + c, bf);
        unsigned short hi = f2b(d);
        wlhi[L * 2048 + j * 128 + kk] = hi;
        wllo[L * 2048 + j * 128 + kk] = f2b(d - b2f(hi));
        return;
    }
    i -= 2048;
    if (i < 2048) {     // zero rows j>=8, layers 1-2
        int L = 1 + (i >> 10), rem = i & 1023, j = 8 + (rem >> 7), kk = rem & 127;
        wlhi[L * 2048 + j * 128 + kk] = 0;
        wllo[L * 2048 + j * 128 + kk] = 0;
    }
}

// ------------------------------------------------------------ graph build
__global__ void k_graph(const int* __restrict__ ei, const int* __restrict__ shock,
                        float* __restrict__ down, int* __restrict__ deg) {
    int e = blockIdx.x * blockDim.x + threadIdx.x;
    if (e < ETOT) {
        int d = (e < N_EDGES) ? ei[N_EDGES + e] : (e - N_EDGES);
        atomicAdd(&deg[d], 1);
        if (e < N_EDGES && shock[ei[e]] != 0) down[d] = 1.f;
    }
}

// ------------------------------------------------------------ scan (2-phase)
__global__ __launch_bounds__(256) void k_scan1(
        const int* __restrict__ deg, int* __restrict__ bsum) {
    __shared__ int red[4];
    int b = blockIdx.x, t = threadIdx.x, lane = t & 63, w = t >> 6;
    int idx = b * 256 + t;
    int v = (idx < N_NODES) ? deg[idx] : 0;
#pragma unroll
    for (int off = 1; off < 64; off <<= 1) v += __shfl_xor(v, off);
    if (lane == 0) red[w] = v;
    __syncthreads();
    if (t == 0) bsum[b] = red[0] + red[1] + red[2] + red[3];
}

__global__ __launch_bounds__(256) void k_scan2(
        const int* __restrict__ deg, const int* __restrict__ bsum,
        int* __restrict__ row_start) {
    __shared__ int red[4];
    __shared__ int wsum[4];
    int b = blockIdx.x, t = threadIdx.x, lane = t & 63, w = t >> 6;
    int pv = (t < b) ? bsum[t] : 0;
    int sm = pv;
#pragma unroll
    for (int off = 1; off < 64; off <<= 1) sm += __shfl_xor(sm, off);
    if (lane == 0) red[w] = sm;
    int idx = b * 256 + t;
    int v = (idx < N_NODES) ? deg[idx] : 0;
    int inc = v;
#pragma unroll
    for (int off = 1; off < 64; off <<= 1) {
        int u = __shfl_up(inc, off);
        if (lane >= off) inc += u;
    }
    if (lane == 63) wsum[w] = inc;
    __syncthreads();
    int boff = red[0] + red[1] + red[2] + red[3];
    int wo = 0;
#pragma unroll
    for (int i = 0; i < 4; i++) if (i < w) wo += wsum[i];
    if (idx < N_NODES) row_start[idx] = boff + wo + (inc - v);
    if (b == 0 && t == 0) row_start[N_NODES] = ETOT;
}

__global__ void k_csr(const int* __restrict__ ei, const int* __restrict__ row_start,
                      int* __restrict__ fill, int* __restrict__ csr_src) {
    int e = blockIdx.x * blockDim.x + threadIdx.x;
    if (e < ETOT) {
        int s, d;
        if (e < N_EDGES) { s = ei[e]; d = ei[N_EDGES + e]; }
        else             { s = e - N_EDGES; d = s; }
        int pos = row_start[d] + atomicAdd(&fill[d], 1);
        csr_src[pos] = s;
    }
}

// ------------------------------------------------------------ encoder -> h bf16
__global__ __launch_bounds__(256) void k_encoder(
        const void* __restrict__ xraw, const int* __restrict__ flag,
        const int* __restrict__ shock, const float* __restrict__ down,
        const float* __restrict__ enc_w, const float* __restrict__ enc_b,
        const float* __restrict__ ln_g, const float* __restrict__ ln_b,
        unsigned short* __restrict__ h) {
    __shared__ float sw[2304];
    __shared__ float sp[384];
    int t = threadIdx.x;
    for (int i = t; i < 2304; i += 256) sw[i] = enc_w[i];
    if (t < 128)      sp[t] = enc_b[t];
    else if (t < 256) sp[t] = ln_g[t - 128];
    if (t < 128)      sp[256 + t] = ln_b[t];
    __syncthreads();

    int w = t >> 6, l = t & 63;
    int n = blockIdx.x * 4 + w;
    int bf = flag[0];
    int c0 = 2 * l, c1 = c0 + 1;

    float xv = (l < 16) ? pread(xraw, (size_t)n * 16 + l, bf) : 0.f;
    float xs = (float)shock[n];
    float xd = down[n];

    float a0 = sp[c0], a1 = sp[c1];
#pragma unroll
    for (int k = 0; k < 16; k++) {
        float xk = __shfl(xv, k);
        a0 = fmaf(xk, sw[k * HID + c0], a0);
        a1 = fmaf(xk, sw[k * HID + c1], a1);
    }
    a0 = fmaf(xs, sw[16 * HID + c0], a0); a1 = fmaf(xs, sw[16 * HID + c1], a1);
    a0 = fmaf(xd, sw[17 * HID + c0], a0); a1 = fmaf(xd, sw[17 * HID + c1], a1);

    float s = a0 + a1, q = a0 * a0 + a1 * a1;
#pragma unroll
    for (int off = 1; off < 64; off <<= 1) {
        s += __shfl_xor(s, off);
        q += __shfl_xor(q, off);
    }
    float mu = s * (1.f / 128.f);
    float var = q * (1.f / 128.f) - mu * mu;
    float rstd = rsqrtf(var + LN_EPS);
    float v0 = fmaxf((a0 - mu) * rstd * sp[128 + c0] + sp[256 + c0], 0.f);
    float v1 = fmaxf((a1 - mu) * rstd * sp[128 + c1] + sp[256 + c1], 0.f);
    *(unsigned int*)&h[(size_t)n * HID + c0] = pack2(v0, v1);
}

// ------------------------------------------------------------ attention logits
__global__ __launch_bounds__(256) void k_logits(
        const unsigned short* __restrict__ h, const float* __restrict__ wl,
        float* __restrict__ al_s, float* __restrict__ al_d) {
    __shared__ float wls[1024];
    int t = threadIdx.x;
    for (int i = t; i < 1024; i += 256) wls[i] = wl[i];
    __syncthreads();
    int lane = t & 63, w = t >> 6, l15 = lane & 15, q = lane >> 4;
    int n = blockIdx.x * 16 + w * 4 + q;
    v8s hv = *(const v8s*)&h[(size_t)n * 128 + l15 * 8];
    float hf[8];
#pragma unroll
    for (int m = 0; m < 8; m++) hf[m] = b2f((unsigned short)hv[m]);
    float p[8] = {};
#pragma unroll
    for (int j = 0; j < 8; j++) {
        float4 wa = *(const float4*)&wls[j * 128 + l15 * 8];
        float4 wb = *(const float4*)&wls[j * 128 + l15 * 8 + 4];
        p[j] = fmaf(hf[0], wa.x, p[j]); p[j] = fmaf(hf[1], wa.y, p[j]);
        p[j] = fmaf(hf[2], wa.z, p[j]); p[j] = fmaf(hf[3], wa.w, p[j]);
        p[j] = fmaf(hf[4], wb.x, p[j]); p[j] = fmaf(hf[5], wb.y, p[j]);
        p[j] = fmaf(hf[6], wb.z, p[j]); p[j] = fmaf(hf[7], wb.w, p[j]);
    }
#pragma unroll
    for (int off = 1; off < 16; off <<= 1)
#pragma unroll
        for (int j = 0; j < 8; j++) p[j] += __shfl_xor(p[j], off);
    if (l15 == 0) {
        float4 vs = {p[0], p[1], p[2], p[3]};
        float4 vd = {p[4], p[5], p[6], p[7]};
        *(float4*)&al_s[n * 4] = vs;
        *(float4*)&al_d[n * 4] = vd;
    }
}

// ------------------------------------------------------------ aggregation v4
__global__ __launch_bounds__(256) void k_agg4(
        const unsigned short* __restrict__ h, const float* __restrict__ al_src,
        const float* __restrict__ al_dst,
        const int* __restrict__ row_start, const int* __restrict__ csr_src,
        unsigned short* __restrict__ agg) {
    int w = threadIdx.x >> 6, l = threadIdx.x & 63;
    int n = blockIdx.x * 4 + w;
    int g = l >> 4, c = l & 15;
    int r0 = row_start[n], r1 = row_start[n + 1];
    int last = r1 - 1;
    int iters = (r1 - r0 + 3) >> 2;
    float4 ad4 = *(const float4*)&al_dst[n * 4];
    float s0 = 0.f, s1 = 0.f, s2 = 0.f, s3 = 0.f;
    float acc[4][8] = {};

    int j0 = r0 + g;
    int vC = (j0 <= last) ? 1 : 0;
    int jc = vC ? j0 : last;
    int iC = csr_src[jc];
    float4 aC = *(const float4*)&al_src[iC * 4];
    v8s hC = *(const v8s*)&h[(size_t)iC * 128 + c * 8];

#pragma unroll 1
    for (int it = 0; it < iters; it++) {
        float4 aN = aC; v8s hN = hC; int vN = 0;
        if (it + 1 < iters) {                       // wave-uniform branch
            int jn = r0 + (it + 1) * 4 + g;
            vN = (jn <= last) ? 1 : 0;
            jn = vN ? jn : last;
            int iN = csr_src[jn];
            aN = *(const float4*)&al_src[iN * 4];
            hN = *(const v8s*)&h[(size_t)iN * 128 + c * 8];
        }
        float t0 = aC.x + ad4.x; t0 = (t0 >= 0.f) ? t0 : NEG * t0;
        float t1 = aC.y + ad4.y; t1 = (t1 >= 0.f) ? t1 : NEG * t1;
        float t2 = aC.z + ad4.z; t2 = (t2 >= 0.f) ? t2 : NEG * t2;
        float t3 = aC.w + ad4.w; t3 = (t3 >= 0.f) ? t3 : NEG * t3;
        float m = (float)vC;
        float e0 = __expf(t0) * m, e1 = __expf(t1) * m,
              e2 = __expf(t2) * m, e3 = __expf(t3) * m;
        s0 += e0; s1 += e1; s2 += e2; s3 += e3;
#pragma unroll
        for (int i = 0; i < 8; i++) {
            float hv = b2f((unsigned short)hC[i]);
            acc[0][i] = fmaf(e0, hv, acc[0][i]);
            acc[1][i] = fmaf(e1, hv, acc[1][i]);
            acc[2][i] = fmaf(e2, hv, acc[2][i]);
            acc[3][i] = fmaf(e3, hv, acc[3][i]);
        }
        aC = aN; hC = hN; vC = vN;
    }
    s0 += __shfl_xor(s0, 16); s0 += __shfl_xor(s0, 32);
    s1 += __shfl_xor(s1, 16); s1 += __shfl_xor(s1, 32);
    s2 += __shfl_xor(s2, 16); s2 += __shfl_xor(s2, 32);
    s3 += __shfl_xor(s3, 16); s3 += __shfl_xor(s3, 32);
#pragma unroll
    for (int hh = 0; hh < 4; hh++)
#pragma unroll
        for (int i = 0; i < 8; i++) {
            acc[hh][i] += __shfl_xor(acc[hh][i], 16);
            acc[hh][i] += __shfl_xor(acc[hh][i], 32);
        }
    float sg = (g == 0) ? s0 : (g == 1) ? s1 : (g == 2) ? s2 : s3;
    float inv = 1.f / (sg + 1e-16f);
    short o[8];
#pragma unroll
    for (int i = 0; i < 8; i++) {
        float av = (g == 0) ? acc[0][i] : (g == 1) ? acc[1][i]
                 : (g == 2) ? acc[2][i] : acc[3][i];
        o[i] = (short)f2b(av * inv);
    }
    *(v8s*)&agg[(size_t)n * 512 + g * 128 + c * 8] = *(const v8s*)o;
}

// ------------------------------------------------------------ K=512 GEMM + BN
__global__ __launch_bounds__(256, 4) void k_gemm2(
        const unsigned short* __restrict__ A,     // agg [N][512]
        const unsigned short* __restrict__ Wt,    // [128][512]
        const float* __restrict__ bias,
        const float* __restrict__ bn_g, const float* __restrict__ bn_b,
        const float* __restrict__ bn_m, const float* __restrict__ bn_v,
        unsigned short* __restrict__ hout, int relu_flag,
        const unsigned short* __restrict__ wlhi,  // [16][128]
        const unsigned short* __restrict__ wllo,  // [16][128]
        float* __restrict__ al_s, float* __restrict__ al_d, int logit_flag) {
    __shared__ __align__(16) unsigned short As[2][64 * 136];
    int t = threadIdx.x;
    int lane = t & 63, w = t >> 6, l15 = lane & 15, q = lane >> 4;
    int m0 = blockIdx.x * 64;
    int c0 = w * 32 + 2 * l15, c1 = c0 + 1;

    v8s st[4];
#pragma unroll
    for (int it = 0; it < 4; it++) {
        int cc = t + it * 256, row = cc >> 4, ch = cc & 15;
        v8s val = {0, 0, 0, 0, 0, 0, 0, 0};
        if (m0 + row < N_NODES)
            val = *(const v8s*)&A[(size_t)(m0 + row) * 512 + ch * 8];
        st[it] = val;
    }
#pragma unroll
    for (int it = 0; it < 4; it++) {
        int cc = t + it * 256, row = cc >> 4, ch = cc & 15;
        *(v8s*)&As[0][row * 136 + ch * 8] = st[it];
    }
    __syncthreads();

    v4f acc[4][2] = {};
#pragma unroll
    for (int kc = 0; kc < 4; kc++) {
        if (kc < 3) {
#pragma unroll
            for (int it = 0; it < 4; it++) {
                int cc = t + it * 256, row = cc >> 4, ch = cc & 15;
                v8s val = {0, 0, 0, 0, 0, 0, 0, 0};
                if (m0 + row < N_NODES)
                    val = *(const v8s*)&A[(size_t)(m0 + row) * 512
                                          + (kc + 1) * 128 + ch * 8];
                st[it] = val;
            }
        }
#pragma unroll
        for (int kt = 0; kt < 4; kt++) {
            v8s b0 = *(const v8s*)&Wt[(size_t)c0 * 512 + kc * 128 + kt * 32 + q * 8];
            v8s b1 = *(const v8s*)&Wt[(size_t)c1 * 512 + kc * 128 + kt * 32 + q * 8];
#pragma unroll
            for (int mt = 0; mt < 4; mt++) {
                v8s a = *(const v8s*)&As[kc & 1][(mt * 16 + l15) * 136
                                                 + kt * 32 + q * 8];
                acc[mt][0] = MFMA(a, b0, acc[mt][0]);
                acc[mt][1] = MFMA(a, b1, acc[mt][1]);
            }
        }
        if (kc < 3) {
#pragma unroll
            for (int it = 0; it < 4; it++) {
                int cc = t + it * 256, row = cc >> 4, ch = cc & 15;
                *(v8s*)&As[(kc + 1) & 1][row * 136 + ch * 8] = st[it];
            }
        }
        __syncthreads();
    }

    float bi0 = bias[c0], bi1 = bias[c1];
    float sc0 = rsqrtf(bn_v[c0] + LN_EPS) * bn_g[c0];
    float sc1 = rsqrtf(bn_v[c1] + LN_EPS) * bn_g[c1];
    float sh0 = bn_b[c0] - bn_m[c0] * sc0;
    float sh1 = bn_b[c1] - bn_m[c1] * sc1;
#pragma unroll
    for (int mt = 0; mt < 4; mt++)
#pragma unroll
        for (int r = 0; r < 4; r++) {
            int row = mt * 16 + q * 4 + r;
            int node = m0 + row;
            float v0 = (0.25f * acc[mt][0][r] + bi0) * sc0 + sh0;
            float v1 = (0.25f * acc[mt][1][r] + bi1) * sc1 + sh1;
            if (relu_flag) { v0 = fmaxf(v0, 0.f); v1 = fmaxf(v1, 0.f); }
            unsigned int pv = pack2(v0, v1);
            if (node < N_NODES)
                *(unsigned int*)&hout[(size_t)node * 128 + c0] = pv;
            if (logit_flag)
                *(unsigned int*)&As[0][row * 136 + c0] = pv;
        }

    if (logit_flag) {
        __syncthreads();
        v4f accL = {0.f, 0.f, 0.f, 0.f};
#pragma unroll
        for (int kt = 0; kt < 4; kt++) {
            v8s a  = *(const v8s*)&As[0][(w * 16 + l15) * 136 + kt * 32 + q * 8];
            v8s bh = *(const v8s*)&wlhi[(size_t)l15 * 128 + kt * 32 + q * 8];
            v8s bl = *(const v8s*)&wllo[(size_t)l15 * 128 + kt * 32 + q * 8];
            accL = MFMA(a, bh, accL);
            accL = MFMA(a, bl, accL);
        }
        if (l15 < 8) {
#pragma unroll
            for (int r = 0; r < 4; r++) {
                int node = m0 + w * 16 + q * 4 + r;
                if (node < N_NODES) {
                    if (l15 < 4) al_s[node * 4 + l15] = accL[r];
                    else         al_d[node * 4 + (l15 - 4)] = accL[r];
                }
            }
        }
    }
}

// ------------------------------------------------------------ UV GEMM
__global__ __launch_bounds__(256, 4) void k_uvgemm(
        const unsigned short* __restrict__ A, const unsigned short* __restrict__ Wt,
        unsigned short* __restrict__ UV) {
    __shared__ __align__(16) unsigned short As[64 * 136];
    int t = threadIdx.x;
    int lane = t & 63, w = t >> 6, l15 = lane & 15, q = lane >> 4;
    int m0 = blockIdx.x * 64, n0 = blockIdx.y * 128;
    int c0 = n0 + w * 32 + 2 * l15;

    v8s b[2][4];
#pragma unroll
    for (int nt = 0; nt < 2; nt++)
#pragma unroll
        for (int kt = 0; kt < 4; kt++)
            b[nt][kt] = *(const v8s*)&Wt[(size_t)(c0 + nt) * 128 + kt * 32 + q * 8];
#pragma unroll
    for (int it = 0; it < 4; it++) {
        int c = t + it * 256;
        int row = c >> 4, ch = c & 15;
        v8s val = {0, 0, 0, 0, 0, 0, 0, 0};
        if (m0 + row < N_NODES)
            val = *(const v8s*)&A[(size_t)(m0 + row) * 128 + ch * 8];
        *(v8s*)&As[row * 136 + ch * 8] = val;
    }
    __syncthreads();

    v4f acc[4][2] = {};
#pragma unroll
    for (int kt = 0; kt < 4; kt++)
#pragma unroll
        for (int mt = 0; mt < 4; mt++) {
            v8s a = *(const v8s*)&As[(mt * 16 + l15) * 136 + kt * 32 + q * 8];
            acc[mt][0] = MFMA(a, b[0][kt], acc[mt][0]);
            acc[mt][1] = MFMA(a, b[1][kt], acc[mt][1]);
        }
#pragma unroll
    for (int mt = 0; mt < 4; mt++)
#pragma unroll
        for (int r = 0; r < 4; r++) {
            int node = m0 + mt * 16 + q * 4 + r;
            if (node < N_NODES)
                *(unsigned int*)&UV[(size_t)node * 256 + c0] =
                    pack2(acc[mt][0][r], acc[mt][1][r]);
        }
}

// ------------------------------------------------------------ edge MLP v5
// 512 threads, 64 edges/block (grid 3125), 2 edges per 16-lane group.
__global__ __launch_bounds__(512) void k_edgemlp5(
        const unsigned short* __restrict__ UV, const int* __restrict__ ei,
        const void* __restrict__ eraw, const int* __restrict__ flag,
        const float* __restrict__ w1e, const float* __restrict__ em1b,
        const float* __restrict__ lng, const float* __restrict__ lnb,
        const unsigned short* __restrict__ w2t, const float* __restrict__ em2b,
        const float* __restrict__ em3w, const float* __restrict__ em3b,
        float* __restrict__ out) {
    __shared__ __align__(16) unsigned short za[64 * 136];   // 17408 B
    __shared__ __align__(16) float w1e_s[1024];             // 4096 B
    __shared__ __align__(16) unsigned short ea_s[64 * 8];   // 1024 B
    __shared__ int idx_s[128];
    __shared__ float part[8][32];

    int t = threadIdx.x;
    int lane = t & 63, w = t >> 6, l15 = lane & 15, q = lane >> 4;
    int gg = t >> 4;           // group 0..31
    int e0 = blockIdx.x * 64;
    int bf = flag[0];
    int cb = l15 * 8;          // this lane's 8 channels

    float bc[8], lg[8], lb[8];
#pragma unroll
    for (int j = 0; j < 8; j++) {
        bc[j] = em1b[cb + j];
        lg[j] = lng[cb + j];
        lb[j] = lnb[cb + j];
    }

    for (int i = t; i < 1024; i += 512) w1e_s[i] = w1e[i];
    if (t < 64) {
        idx_s[t * 2]     = ei[e0 + t];
        idx_s[t * 2 + 1] = ei[N_EDGES + e0 + t];
        if (bf) {
            *(v8s*)&ea_s[t * 8] =
                *(const v8s*)((const unsigned short*)eraw + (size_t)(e0 + t) * 8);
        } else {
            short tmp[8];
#pragma unroll
            for (int j = 0; j < 8; j++)
                tmp[j] = (short)f2b(((const float*)eraw)[(size_t)(e0 + t) * 8 + j]);
            *(v8s*)&ea_s[t * 8] = *(const v8s*)tmp;
        }
    }
    __syncthreads();

#pragma unroll 1
    for (int i = 0; i < 2; i++) {
        int el = gg + i * 32;
        int src = idx_s[el * 2], dst = idx_s[el * 2 + 1];
        v8s uu = *(const v8s*)&UV[(size_t)src * 256 + cb];
        v8s vv = *(const v8s*)&UV[(size_t)dst * 256 + 128 + cb];
        v8s ea8 = *(const v8s*)&ea_s[el * 8];
        float eaf[8];
#pragma unroll
        for (int k = 0; k < 8; k++) eaf[k] = b2f((unsigned short)ea8[k]);
        float e[8] = {};
#pragma unroll
        for (int k = 0; k < 8; k++) {
            float4 wa = *(const float4*)&w1e_s[k * 128 + cb];
            float4 wb = *(const float4*)&w1e_s[k * 128 + cb + 4];
            e[0] = fmaf(eaf[k], wa.x, e[0]);
            e[1] = fmaf(eaf[k], wa.y, e[1]);
            e[2] = fmaf(eaf[k], wa.z, e[2]);
            e[3] = fmaf(eaf[k], wa.w, e[3]);
            e[4] = fmaf(eaf[k], wb.x, e[4]);
            e[5] = fmaf(eaf[k], wb.y, e[5]);
            e[6] = fmaf(eaf[k], wb.z, e[6]);
            e[7] = fmaf(eaf[k], wb.w, e[7]);
        }
        float z[8];
        float s = 0.f, qq = 0.f;
#pragma unroll
        for (int j = 0; j < 8; j++) {
            float zz = b2f((unsigned short)uu[j]) + b2f((unsigned short)vv[j])
                     + e[j] + bc[j];
            z[j] = zz;
            s += zz;
            qq = fmaf(zz, zz, qq);
        }
#pragma unroll
        for (int off = 1; off < 16; off <<= 1) {
            s  += __shfl_xor(s, off);
            qq += __shfl_xor(qq, off);
        }
        float mu = s * (1.f / 128.f);
        float var = qq * (1.f / 128.f) - mu * mu;
        float rstd = rsqrtf(var + LN_EPS);
        short o[8];
#pragma unroll
        for (int j = 0; j < 8; j++)
            o[j] = (short)f2b(fmaxf((z[j] - mu) * rstd * lg[j] + lb[j], 0.f));
        *(v8s*)&za[el * 136 + cb] = *(const v8s*)o;
    }
    __syncthreads();

    // layer 2 MFMA: wave w -> cols (w&3)*16..+15, rows (w>>2)*32..+31
    int cw = w & 3, rh = w >> 2;
    v8s b2v[4];
#pragma unroll
    for (int kt = 0; kt < 4; kt++)
        b2v[kt] = *(const v8s*)&w2t[(size_t)(cw * 16 + l15) * 128 + kt * 32 + q * 8];
    v4f acc2[2] = {};
#pragma unroll
    for (int kt = 0; kt < 4; kt++)
#pragma unroll
        for (int m = 0; m < 2; m++) {
            int mt = rh * 2 + m;
            v8s a = *(const v8s*)&za[(mt * 16 + l15) * 136 + kt * 32 + q * 8];
            acc2[m] = MFMA(a, b2v[kt], acc2[m]);
        }

    {
        int col = cw * 16 + l15;
        float b2c = em2b[col], w3c = em3w[col];
#pragma unroll
        for (int m = 0; m < 2; m++)
#pragma unroll
            for (int r = 0; r < 4; r++) {
                float vv2 = fmaxf(acc2[m][r] + b2c, 0.f) * w3c;
#pragma unroll
                for (int off = 1; off < 16; off <<= 1) vv2 += __shfl_xor(vv2, off);
                if (l15 == 0) part[w][m * 16 + q * 4 + r] = vv2;
            }
    }
    __syncthreads();
    if (t < 64) {
        int half = t >> 5, lr = t & 31;
        out[e0 + t] = part[half * 4 + 0][lr] + part[half * 4 + 1][lr]
                    + part[half * 4 + 2][lr] + part[half * 4 + 3][lr]
                    + em3b[0];
    }
}

// ------------------------------------------------------------ launch
extern "C" __attribute__((visibility("default")))
void kernel_launch(void* const* d_in, const int* in_sizes, int n_in,
                   void* d_out, int out_size, void* d_ws, size_t ws_size,
                   hipStream_t stream) {
    float* out = (float*)d_out;

    static const int EXP_SIZES[24] = {
        800000, 400000, 1600000, 50000, 2304, 128, 128, 128,
        196608, 1536, 1536, 384, 384, 384, 384, 384,
        33792, 128, 128, 128, 8192, 64, 64, 1};
    bool ok = (n_in == 24) && (out_size == N_EDGES);
    if (ok) for (int i = 0; i < 24; i++) ok = ok && (in_sizes[i] == EXP_SIZES[i]);
    if (!ok) {
        k_fill<<<(out_size + 255) / 256, 256, 0, stream>>>(out, out_size, 4.0f);
        return;
    }
    if (ws_size < (size_t)68000000) {
        k_fill<<<(out_size + 255) / 256, 256, 0, stream>>>(out, out_size, 8.0f);
        return;
    }

    const int* ei    = (const int*)d_in[1];
    const int* shock = (const int*)d_in[3];

    char* ws = (char*)d_ws;
    unsigned short* h_bf  = (unsigned short*)(ws + 0);          // 12,800,000
    unsigned short* agg   = (unsigned short*)(ws + 12800000);   // 51,200,000
    unsigned short* UV    = agg;  // aliases agg (agg dead before k_uvgemm)
    float* al_s    = (float*)(ws + 64000000);
    float* al_d    = (float*)(ws + 64800000);
    float* down    = (float*)(ws + 65600000);
    int*   deg     = (int*)  (ws + 65800000);
    int*   row_st  = (int*)  (ws + 66000000);
    int*   fill    = (int*)  (ws + 66200064);
    int*   csr_src = (int*)  (ws + 66400064);
    int*   flag    = (int*)  (ws + 67400064);
    unsigned short* gwt = (unsigned short*)(ws + 67400128);     // 393,216
    unsigned short* uvt = (unsigned short*)(ws + 67793344);     // 65,536
    unsigned short* w2t = (unsigned short*)(ws + 67858880);     // 16,384
    float* pool    = (float*)(ws + 67875264);                   // 9,224 f32
    int*   bsum    = (int*)  (ws + 67912160);                   // 784 B
    float* wl      = (float*)(ws + 67912960);                   // 12,288 B
    unsigned short* wlhi = (unsigned short*)(ws + 67925248);    // 12,288 B
    unsigned short* wllo = (unsigned short*)(ws + 67937536);    // 12,288 B

    float* cencw = pool + 0;    float* cencb = pool + 2304;
    float* cenlg = pool + 2432; float* cenlb = pool + 2560;
    float* cbias = pool + 5760; float* cbng  = pool + 6144;
    float* cbnb  = pool + 6528; float* cbnm  = pool + 6912;
    float* cbnv  = pool + 7296; float* cem1b = pool + 7680;
    float* cemlg = pool + 7808; float* cemlb = pool + 7936;
    float* cem2b = pool + 8064; float* cem3w = pool + 8128;
    float* cem3b = pool + 8192;
    float* w1e   = pool + 8200;   // [8][128] fp32

    k_detect<<<1, 64, 0, stream>>>((const unsigned short*)d_in[0], flag);

    PrepArgs pa;
    pa.encw = d_in[4];  pa.encb = d_in[5];  pa.enlg = d_in[6];  pa.enlb = d_in[7];
    pa.gatw = d_in[8];  pa.asrc = d_in[9];  pa.adst = d_in[10]; pa.bias = d_in[11];
    pa.bng  = d_in[12]; pa.bnb  = d_in[13]; pa.bnm  = d_in[14]; pa.bnv  = d_in[15];
    pa.em1w = d_in[16]; pa.em1b = d_in[17]; pa.emlg = d_in[18]; pa.emlb = d_in[19];
    pa.em2w = d_in[20]; pa.em2b = d_in[21]; pa.em3w = d_in[22]; pa.em3b = d_in[23];
    k_prep<<<(PREP_ITEMS + 255) / 256, 256, 0, stream>>>(
        pa, pool, gwt, uvt, w2t, wl, wlhi, wllo, down, deg, fill, flag);

    k_graph<<<(ETOT + 255) / 256, 256, 0, stream>>>(ei, shock, down, deg);
    k_scan1<<<NSB, 256, 0, stream>>>(deg, bsum);
    k_scan2<<<NSB, 256, 0, stream>>>(deg, bsum, row_st);
    k_csr<<<(ETOT + 255) / 256, 256, 0, stream>>>(ei, row_st, fill, csr_src);
    k_encoder<<<N_NODES / 4, 256, 0, stream>>>(
        d_in[0], flag, shock, down, cencw, cencb, cenlg, cenlb, h_bf);
    k_logits<<<N_NODES / 16, 256, 0, stream>>>(h_bf, wl, al_s, al_d);
    for (int i = 0; i < 3; i++) {
        k_agg4<<<N_NODES / 4, 256, 0, stream>>>(
            h_bf, al_s, al_d, row_st, csr_src, agg);
        k_gemm2<<<782, 256, 0, stream>>>(
            agg, gwt + (size_t)i * 65536,
            cbias + i * 128, cbng + i * 128, cbnb + i * 128,
            cbnm + i * 128, cbnv + i * 128, h_bf, (i < 2) ? 1 : 0,
            wlhi + (size_t)(i + 1) * 2048, wllo + (size_t)(i + 1) * 2048,
            al_s, al_d, (i < 2) ? 1 : 0);
    }
    k_uvgemm<<<dim3(782, 2), 256, 0, stream>>>(h_bf, uvt, UV);
    k_edgemlp5<<<N_EDGES / 64, 512, 0, stream>>>(
        UV, ei, d_in[2], flag, w1e, cem1b, cemlg, cemlb,
        w2t, cem2b, cem3w, cem3b, out);
}

// Round 6
// 464.809 us; speedup vs baseline: 1.0337x; 1.0249x over previous
//
#include <hip/hip_runtime.h>
#include <hip/hip_bf16.h>

// ShockPropagationGNN — round 19 (revert to r13 core = best 462-465us).
// r14-r18 post-mortem: the GAT restructure (logits/agg4/gemm2) and all three
// edgemlp shapes (v4 16-edge, v5 2x32) were net-negative; r13 retained.
// One change vs r13: k_edgemlp3 moves bc/lg/lb (24 live VGPRs) into LDS.
// VGPR 76 -> target <=64 => waves/SIMD 4 -> 8 (LDS then caps 6 blocks/CU).

#define N_NODES 50000
#define N_EDGES 200000
#define ETOT    (N_EDGES + N_NODES)
#define HID     128
#define LN_EPS  1e-5f
#define NEG     0.2f
#define NSB     196

typedef __hip_bfloat16 bf16;
typedef __attribute__((ext_vector_type(8))) short v8s;
typedef __attribute__((ext_vector_type(4))) float v4f;
#define MFMA(a, b, c) __builtin_amdgcn_mfma_f32_16x16x32_bf16(a, b, c, 0, 0, 0)

__device__ __forceinline__ float b2f(unsigned short s) {
    return __uint_as_float(((unsigned int)s) << 16);
}
__device__ __forceinline__ unsigned short f2b(float f) {
    __hip_bfloat16 h = __float2bfloat16(f);
    return *reinterpret_cast<unsigned short*>(&h);
}
__device__ __forceinline__ unsigned int pack2(float a, float b) {
    return (unsigned int)f2b(a) | ((unsigned int)f2b(b) << 16);
}
__device__ __forceinline__ float pread(const void* p, size_t i, int isbf) {
    if (isbf) return b2f(((const unsigned short*)p)[i]);
    return ((const float*)p)[i];
}

__global__ void k_fill(float* out, int n, float v) {
    int i = blockIdx.x * blockDim.x + threadIdx.x;
    if (i < n) out[i] = v;
}

// ------------------------------------------------------------ dtype detect
__global__ void k_detect(const unsigned short* __restrict__ xbuf,
                         int* __restrict__ flag) {
    int sane = 0;
    for (int j = threadIdx.x; j < 4096; j += 64) {
        unsigned short v = xbuf[2 * j];
        int e = (v >> 7) & 0xFF;
        if (v == 0 || (e > 96 && e < 160)) sane++;
    }
    for (int off = 32; off > 0; off >>= 1) sane += __shfl_down(sane, off);
    if (threadIdx.x == 0) flag[0] = (sane * 10 >= 4096 * 9) ? 1 : 0;
}

// ------------------------------------------------------------ prep (fused)
struct PrepArgs {
    const void *encw, *encb, *enlg, *enlb, *gatw, *asrc, *adst, *bias,
               *bng, *bnb, *bnm, *bnv, *em1w, *em1b, *emlg, *emlb,
               *em2w, *em2b, *em3w, *em3b;
};
// zeros | pool | w1e(fp32) | gwt | uvt | w2t
#define PREP_ITEMS (150000 + 8193 + 1024 + 196608 + 32768 + 8192)
__global__ void k_prep(PrepArgs a, float* __restrict__ pool,
                       unsigned short* __restrict__ gwt,   // [L][n=512][k=128]
                       unsigned short* __restrict__ uvt,   // [n=256][k=128]
                       unsigned short* __restrict__ w2t,   // [n=64][k=128]
                       float* __restrict__ down, int* __restrict__ deg,
                       int* __restrict__ fill, const int* __restrict__ flag) {
    int i = blockIdx.x * 256 + threadIdx.x;
    int bf = flag[0];
    if (i < 150000) {
        int which = i / 50000, idx = i - which * 50000;
        if (which == 0) down[idx] = 0.f;
        else if (which == 1) deg[idx] = 0;
        else fill[idx] = 0;
        return;
    }
    i -= 150000;
    if (i < 8193) {
        const void* s; int off;
        if      (i < 2304) { s = a.encw; off = 0;    }
        else if (i < 2432) { s = a.encb; off = 2304; }
        else if (i < 2560) { s = a.enlg; off = 2432; }
        else if (i < 2688) { s = a.enlb; off = 2560; }
        else if (i < 4224) { s = a.asrc; off = 2688; }
        else if (i < 5760) { s = a.adst; off = 4224; }
        else if (i < 6144) { s = a.bias; off = 5760; }
        else if (i < 6528) { s = a.bng;  off = 6144; }
        else if (i < 6912) { s = a.bnb;  off = 6528; }
        else if (i < 7296) { s = a.bnm;  off = 6912; }
        else if (i < 7680) { s = a.bnv;  off = 7296; }
        else if (i < 7808) { s = a.em1b; off = 7680; }
        else if (i < 7936) { s = a.emlg; off = 7808; }
        else if (i < 8064) { s = a.emlb; off = 7936; }
        else if (i < 8128) { s = a.em2b; off = 8064; }
        else if (i < 8192) { s = a.em3w; off = 8128; }
        else               { s = a.em3b; off = 8192; }
        pool[i] = pread(s, i - off, bf);
        return;
    }
    i -= 8193;
    if (i < 1024) {     // w1e fp32: pool[8200 + k*128+c] = em1_w[256+k][c]
        int k = i >> 7, c = i & 127;
        pool[8200 + i] = pread(a.em1w, (size_t)(256 + k) * 128 + c, bf);
        return;
    }
    i -= 1024;
    if (i < 196608) {   // gwt[L][n][k] = gat_w[L][k][n]
        int L = i >> 16, rem = i & 65535, n = rem >> 7, k = rem & 127;
        gwt[i] = f2b(pread(a.gatw, (size_t)L * 65536 + (size_t)k * 512 + n, bf));
        return;
    }
    i -= 196608;
    if (i < 32768) {    // uvt[n][k]: n<128 -> em1_w[k][n]; else em1_w[128+k][n-128]
        int n = i >> 7, k = i & 127;
        float v = (n < 128) ? pread(a.em1w, (size_t)k * 128 + n, bf)
                            : pread(a.em1w, (size_t)(128 + k) * 128 + (n - 128), bf);
        uvt[i] = f2b(v);
        return;
    }
    i -= 32768;
    if (i < 8192) {     // w2t[n][k] = em2_w[k][n]
        int n = i >> 7, k = i & 127;
        w2t[i] = f2b(pread(a.em2w, (size_t)k * 64 + n, bf));
    }
}

// ------------------------------------------------------------ graph build
__global__ void k_graph(const int* __restrict__ ei, const int* __restrict__ shock,
                        float* __restrict__ down, int* __restrict__ deg) {
    int e = blockIdx.x * blockDim.x + threadIdx.x;
    if (e < ETOT) {
        int d = (e < N_EDGES) ? ei[N_EDGES + e] : (e - N_EDGES);
        atomicAdd(&deg[d], 1);
        if (e < N_EDGES && shock[ei[e]] != 0) down[d] = 1.f;
    }
}

// ------------------------------------------------------------ scan (2-phase)
__global__ __launch_bounds__(256) void k_scan1(
        const int* __restrict__ deg, int* __restrict__ bsum) {
    __shared__ int red[4];
    int b = blockIdx.x, t = threadIdx.x, lane = t & 63, w = t >> 6;
    int idx = b * 256 + t;
    int v = (idx < N_NODES) ? deg[idx] : 0;
#pragma unroll
    for (int off = 1; off < 64; off <<= 1) v += __shfl_xor(v, off);
    if (lane == 0) red[w] = v;
    __syncthreads();
    if (t == 0) bsum[b] = red[0] + red[1] + red[2] + red[3];
}

__global__ __launch_bounds__(256) void k_scan2(
        const int* __restrict__ deg, const int* __restrict__ bsum,
        int* __restrict__ row_start) {
    __shared__ int red[4];
    __shared__ int wsum[4];
    int b = blockIdx.x, t = threadIdx.x, lane = t & 63, w = t >> 6;
    int pv = (t < b) ? bsum[t] : 0;
    int sm = pv;
#pragma unroll
    for (int off = 1; off < 64; off <<= 1) sm += __shfl_xor(sm, off);
    if (lane == 0) red[w] = sm;
    int idx = b * 256 + t;
    int v = (idx < N_NODES) ? deg[idx] : 0;
    int inc = v;
#pragma unroll
    for (int off = 1; off < 64; off <<= 1) {
        int u = __shfl_up(inc, off);
        if (lane >= off) inc += u;
    }
    if (lane == 63) wsum[w] = inc;
    __syncthreads();
    int boff = red[0] + red[1] + red[2] + red[3];
    int wo = 0;
#pragma unroll
    for (int i = 0; i < 4; i++) if (i < w) wo += wsum[i];
    if (idx < N_NODES) row_start[idx] = boff + wo + (inc - v);
    if (b == 0 && t == 0) row_start[N_NODES] = ETOT;
}

__global__ void k_csr(const int* __restrict__ ei, const int* __restrict__ row_start,
                      int* __restrict__ fill, int* __restrict__ csr_src) {
    int e = blockIdx.x * blockDim.x + threadIdx.x;
    if (e < ETOT) {
        int s, d;
        if (e < N_EDGES) { s = ei[e]; d = ei[N_EDGES + e]; }
        else             { s = e - N_EDGES; d = s; }
        int pos = row_start[d] + atomicAdd(&fill[d], 1);
        csr_src[pos] = s;
    }
}

// ------------------------------------------------------------ encoder -> h bf16
__global__ __launch_bounds__(256) void k_encoder(
        const void* __restrict__ xraw, const int* __restrict__ flag,
        const int* __restrict__ shock, const float* __restrict__ down,
        const float* __restrict__ enc_w, const float* __restrict__ enc_b,
        const float* __restrict__ ln_g, const float* __restrict__ ln_b,
        unsigned short* __restrict__ h) {
    __shared__ float sw[2304];
    __shared__ float sp[384];
    int t = threadIdx.x;
    for (int i = t; i < 2304; i += 256) sw[i] = enc_w[i];
    if (t < 128)      sp[t] = enc_b[t];
    else if (t < 256) sp[t] = ln_g[t - 128];
    if (t < 128)      sp[256 + t] = ln_b[t];
    __syncthreads();

    int w = t >> 6, l = t & 63;
    int n = blockIdx.x * 4 + w;
    int bf = flag[0];
    int c0 = 2 * l, c1 = c0 + 1;

    float xv = (l < 16) ? pread(xraw, (size_t)n * 16 + l, bf) : 0.f;
    float xs = (float)shock[n];
    float xd = down[n];

    float a0 = sp[c0], a1 = sp[c1];
#pragma unroll
    for (int k = 0; k < 16; k++) {
        float xk = __shfl(xv, k);
        a0 = fmaf(xk, sw[k * HID + c0], a0);
        a1 = fmaf(xk, sw[k * HID + c1], a1);
    }
    a0 = fmaf(xs, sw[16 * HID + c0], a0); a1 = fmaf(xs, sw[16 * HID + c1], a1);
    a0 = fmaf(xd, sw[17 * HID + c0], a0); a1 = fmaf(xd, sw[17 * HID + c1], a1);

    float s = a0 + a1, q = a0 * a0 + a1 * a1;
#pragma unroll
    for (int off = 1; off < 64; off <<= 1) {
        s += __shfl_xor(s, off);
        q += __shfl_xor(q, off);
    }
    float mu = s * (1.f / 128.f);
    float var = q * (1.f / 128.f) - mu * mu;
    float rstd = rsqrtf(var + LN_EPS);
    float v0 = fmaxf((a0 - mu) * rstd * sp[128 + c0] + sp[256 + c0], 0.f);
    float v1 = fmaxf((a1 - mu) * rstd * sp[128 + c1] + sp[256 + c1], 0.f);
    *(unsigned int*)&h[(size_t)n * HID + c0] = pack2(v0, v1);
}

// ------------------------------------------------------------ GAT GEMM + logits
__global__ __launch_bounds__(256, 4) void k_gemm(
        const unsigned short* __restrict__ A, const unsigned short* __restrict__ Wt,
        const float* __restrict__ asrc, const float* __restrict__ adst,
        unsigned short* __restrict__ C,
        float* __restrict__ al_s, float* __restrict__ al_d) {
    __shared__ __align__(16) unsigned short As[64 * 136];
    __shared__ float alp[64][4][2];
    int t = threadIdx.x;
    int lane = t & 63, w = t >> 6, l15 = lane & 15, q = lane >> 4;
    int m0 = blockIdx.x * 64, n0 = blockIdx.y * 128, head = blockIdx.y;
    int c0 = n0 + w * 32 + 2 * l15, c1 = c0 + 1;

    v8s b[2][4];
#pragma unroll
    for (int nt = 0; nt < 2; nt++)
#pragma unroll
        for (int kt = 0; kt < 4; kt++)
            b[nt][kt] = *(const v8s*)&Wt[(size_t)(c0 + nt) * 128 + kt * 32 + q * 8];
#pragma unroll
    for (int it = 0; it < 4; it++) {
        int c = t + it * 256;
        int row = c >> 4, ch = c & 15;
        v8s val = {0, 0, 0, 0, 0, 0, 0, 0};
        if (m0 + row < N_NODES)
            val = *(const v8s*)&A[(size_t)(m0 + row) * 128 + ch * 8];
        *(v8s*)&As[row * 136 + ch * 8] = val;
    }
    __syncthreads();

    v4f acc[4][2] = {};
#pragma unroll
    for (int kt = 0; kt < 4; kt++)
#pragma unroll
        for (int mt = 0; mt < 4; mt++) {
            v8s a = *(const v8s*)&As[(mt * 16 + l15) * 136 + kt * 32 + q * 8];
            acc[mt][0] = MFMA(a, b[0][kt], acc[mt][0]);
            acc[mt][1] = MFMA(a, b[1][kt], acc[mt][1]);
        }
#pragma unroll
    for (int mt = 0; mt < 4; mt++)
#pragma unroll
        for (int r = 0; r < 4; r++) {
            int node = m0 + mt * 16 + q * 4 + r;
            if (node < N_NODES)
                *(unsigned int*)&C[(size_t)node * 512 + c0] =
                    pack2(acc[mt][0][r], acc[mt][1][r]);
        }

    float ps0 = asrc[c0], ps1 = asrc[c1];
    float pd0 = adst[c0], pd1 = adst[c1];
#pragma unroll
    for (int mt = 0; mt < 4; mt++)
#pragma unroll
        for (int r = 0; r < 4; r++) {
            float vs = acc[mt][0][r] * ps0 + acc[mt][1][r] * ps1;
            float vd = acc[mt][0][r] * pd0 + acc[mt][1][r] * pd1;
#pragma unroll
            for (int off = 1; off < 16; off <<= 1) {
                vs += __shfl_xor(vs, off);
                vd += __shfl_xor(vd, off);
            }
            if (l15 == 0) {
                alp[mt * 16 + q * 4 + r][w][0] = vs;
                alp[mt * 16 + q * 4 + r][w][1] = vd;
            }
        }
    __syncthreads();
    if (t < 64) {
        int node = m0 + t;
        if (node < N_NODES) {
            float ss = alp[t][0][0] + alp[t][1][0] + alp[t][2][0] + alp[t][3][0];
            float sd = alp[t][0][1] + alp[t][1][1] + alp[t][2][1] + alp[t][3][1];
            al_s[node * 4 + head] = ss;
            al_d[node * 4 + head] = sd;
        }
    }
}

// ------------------------------------------------------------ aggregation
// wave per node, single-pass softmax; depth-2 index / depth-1 data prefetch.
__global__ __launch_bounds__(256) void k_aggregate(
        const unsigned short* __restrict__ xh, const float* __restrict__ al_src,
        const float* __restrict__ al_dst,
        const int* __restrict__ row_start, const int* __restrict__ csr_src,
        const float* __restrict__ bias,
        const float* __restrict__ bn_g, const float* __restrict__ bn_b,
        const float* __restrict__ bn_m, const float* __restrict__ bn_v,
        unsigned short* __restrict__ h, int relu_flag) {
    int w = threadIdx.x >> 6, l = threadIdx.x & 63;
    int n = blockIdx.x * 4 + w;
    int hh = l >> 4, c8 = l & 15;
    int r0 = row_start[n], r1 = row_start[n + 1];
    float ad = al_dst[n * 4 + hh];
    float sh = 0.f;
    float acc[8] = {};
    int last = r1 - 1;
    int i0 = csr_src[r0];                          // deg >= 1 (self loop)
    int i1 = csr_src[(r0 + 1 < r1) ? r0 + 1 : last];
    float aC = al_src[i0 * 4 + hh];
    v8s rC = *(const v8s*)&xh[(size_t)i0 * 512 + l * 8];
    for (int j = r0; j < r1; j++) {
        int i2 = csr_src[(j + 2 < r1) ? j + 2 : last];
        float aN = al_src[i1 * 4 + hh];
        v8s rN = *(const v8s*)&xh[(size_t)i1 * 512 + l * 8];
        float a = aC + ad;
        a = (a >= 0.f) ? a : NEG * a;
        float we = __expf(a);
        sh += we;
#pragma unroll
        for (int i = 0; i < 8; i++)
            acc[i] = fmaf(we, b2f((unsigned short)rC[i]), acc[i]);
        aC = aN; rC = rN; i1 = i2;
    }
    float inv = 1.f / (sh + 1e-16f);
#pragma unroll
    for (int i = 0; i < 8; i++) {
        acc[i] *= inv;
        acc[i] += __shfl_xor(acc[i], 16);
        acc[i] += __shfl_xor(acc[i], 32);
    }
    if (hh == 0) {
        int cbase = c8 * 8;
        short o[8];
#pragma unroll
        for (int i = 0; i < 8; i++) {
            int c = cbase + i;
            float v = 0.25f * acc[i] + bias[c];
            v = (v - bn_m[c]) * rsqrtf(bn_v[c] + LN_EPS) * bn_g[c] + bn_b[c];
            if (relu_flag) v = fmaxf(v, 0.f);
            o[i] = (short)f2b(v);
        }
        *(v8s*)&h[(size_t)n * 128 + cbase] = *(const v8s*)o;
    }
}

// ------------------------------------------------------------ UV GEMM
__global__ __launch_bounds__(256, 4) void k_uvgemm(
        const unsigned short* __restrict__ A, const unsigned short* __restrict__ Wt,
        unsigned short* __restrict__ UV) {
    __shared__ __align__(16) unsigned short As[64 * 136];
    int t = threadIdx.x;
    int lane = t & 63, w = t >> 6, l15 = lane & 15, q = lane >> 4;
    int m0 = blockIdx.x * 64, n0 = blockIdx.y * 128;
    int c0 = n0 + w * 32 + 2 * l15;

    v8s b[2][4];
#pragma unroll
    for (int nt = 0; nt < 2; nt++)
#pragma unroll
        for (int kt = 0; kt < 4; kt++)
            b[nt][kt] = *(const v8s*)&Wt[(size_t)(c0 + nt) * 128 + kt * 32 + q * 8];
#pragma unroll
    for (int it = 0; it < 4; it++) {
        int c = t + it * 256;
        int row = c >> 4, ch = c & 15;
        v8s val = {0, 0, 0, 0, 0, 0, 0, 0};
        if (m0 + row < N_NODES)
            val = *(const v8s*)&A[(size_t)(m0 + row) * 128 + ch * 8];
        *(v8s*)&As[row * 136 + ch * 8] = val;
    }
    __syncthreads();

    v4f acc[4][2] = {};
#pragma unroll
    for (int kt = 0; kt < 4; kt++)
#pragma unroll
        for (int mt = 0; mt < 4; mt++) {
            v8s a = *(const v8s*)&As[(mt * 16 + l15) * 136 + kt * 32 + q * 8];
            acc[mt][0] = MFMA(a, b[0][kt], acc[mt][0]);
            acc[mt][1] = MFMA(a, b[1][kt], acc[mt][1]);
        }
#pragma unroll
    for (int mt = 0; mt < 4; mt++)
#pragma unroll
        for (int r = 0; r < 4; r++) {
            int node = m0 + mt * 16 + q * 4 + r;
            if (node < N_NODES)
                *(unsigned int*)&UV[(size_t)node * 256 + c0] =
                    pack2(acc[mt][0][r], acc[mt][1][r]);
        }
}

// ------------------------------------------------------------ edge MLP v3b'
// 16 lanes per edge (4 parallel edges/wave). ea@W1e from fp32 LDS (float4
// reads); LN = 8 reg adds + 4 shfl steps over 16 lanes.
// r19: bc/lg/lb moved from 24 live VGPRs into LDS (prm_s) -> VGPR <= 64.
__global__ __launch_bounds__(256) void k_edgemlp3(
        const unsigned short* __restrict__ UV, const int* __restrict__ ei,
        const void* __restrict__ eraw, const int* __restrict__ flag,
        const float* __restrict__ w1e, const float* __restrict__ em1b,
        const float* __restrict__ lng, const float* __restrict__ lnb,
        const unsigned short* __restrict__ w2t, const float* __restrict__ em2b,
        const float* __restrict__ em3w, const float* __restrict__ em3b,
        float* __restrict__ out) {
    __shared__ __align__(16) unsigned short za[64 * 136];   // 17408 B
    __shared__ __align__(16) float w1e_s[1024];             // 4096 B
    __shared__ __align__(16) float prm_s[384];              // 1536 B
    __shared__ __align__(16) unsigned short ea_s[64 * 8];
    __shared__ int idx_s[128];
    __shared__ float part[4][64];

    int t = threadIdx.x;
    int lane = t & 63, w = t >> 6, l15 = lane & 15, q = lane >> 4;
    int e0 = blockIdx.x * 64;
    int bf = flag[0];
    int cb = l15 * 8;    // this lane's 8 channels

    for (int i = t; i < 1024; i += 256) w1e_s[i] = w1e[i];
    if (t < 128)      prm_s[t] = em1b[t];
    else if (t < 256) prm_s[t] = lng[t - 128];
    if (t < 128)      prm_s[256 + t] = lnb[t];
    if (t < 64) {
        idx_s[t * 2]     = ei[e0 + t];
        idx_s[t * 2 + 1] = ei[N_EDGES + e0 + t];
        if (bf) {
            *(v8s*)&ea_s[t * 8] =
                *(const v8s*)((const unsigned short*)eraw + (size_t)(e0 + t) * 8);
        } else {
            short tmp[8];
#pragma unroll
            for (int j = 0; j < 8; j++)
                tmp[j] = (short)f2b(((const float*)eraw)[(size_t)(e0 + t) * 8 + j]);
            *(v8s*)&ea_s[t * 8] = *(const v8s*)tmp;
        }
    }
    __syncthreads();

#pragma unroll 1
    for (int i = 0; i < 4; i++) {
        int el = w * 16 + i * 4 + q;
        int src = idx_s[el * 2], dst = idx_s[el * 2 + 1];
        v8s uu = *(const v8s*)&UV[(size_t)src * 256 + cb];
        v8s vv = *(const v8s*)&UV[(size_t)dst * 256 + 128 + cb];
        v8s ea8 = *(const v8s*)&ea_s[el * 8];
        float eaf[8];
#pragma unroll
        for (int k = 0; k < 8; k++) eaf[k] = b2f((unsigned short)ea8[k]);
        float e[8] = {};
#pragma unroll
        for (int k = 0; k < 8; k++) {
            float4 wa = *(const float4*)&w1e_s[k * 128 + cb];
            float4 wb = *(const float4*)&w1e_s[k * 128 + cb + 4];
            e[0] = fmaf(eaf[k], wa.x, e[0]);
            e[1] = fmaf(eaf[k], wa.y, e[1]);
            e[2] = fmaf(eaf[k], wa.z, e[2]);
            e[3] = fmaf(eaf[k], wa.w, e[3]);
            e[4] = fmaf(eaf[k], wb.x, e[4]);
            e[5] = fmaf(eaf[k], wb.y, e[5]);
            e[6] = fmaf(eaf[k], wb.z, e[6]);
            e[7] = fmaf(eaf[k], wb.w, e[7]);
        }
        float bcv[8];
        *(float4*)&bcv[0] = *(const float4*)&prm_s[cb];
        *(float4*)&bcv[4] = *(const float4*)&prm_s[cb + 4];
        float z[8];
        float s = 0.f, qq = 0.f;
#pragma unroll
        for (int j = 0; j < 8; j++) {
            float zz = b2f((unsigned short)uu[j]) + b2f((unsigned short)vv[j])
                     + e[j] + bcv[j];
            z[j] = zz;
            s += zz;
            qq = fmaf(zz, zz, qq);
        }
#pragma unroll
        for (int off = 1; off < 16; off <<= 1) {
            s  += __shfl_xor(s, off);
            qq += __shfl_xor(qq, off);
        }
        float mu = s * (1.f / 128.f);
        float var = qq * (1.f / 128.f) - mu * mu;
        float rstd = rsqrtf(var + LN_EPS);
        float lgv[8], lbv[8];
        *(float4*)&lgv[0] = *(const float4*)&prm_s[128 + cb];
        *(float4*)&lgv[4] = *(const float4*)&prm_s[128 + cb + 4];
        *(float4*)&lbv[0] = *(const float4*)&prm_s[256 + cb];
        *(float4*)&lbv[4] = *(const float4*)&prm_s[256 + cb + 4];
        short o[8];
#pragma unroll
        for (int j = 0; j < 8; j++)
            o[j] = (short)f2b(fmaxf((z[j] - mu) * rstd * lgv[j] + lbv[j], 0.f));
        *(v8s*)&za[el * 136 + cb] = *(const v8s*)o;
    }
    __syncthreads();

    // layer 2 MFMA: wave w -> cols w*16..+15
    v8s b2[4];
#pragma unroll
    for (int kt = 0; kt < 4; kt++)
        b2[kt] = *(const v8s*)&w2t[(size_t)(w * 16 + l15) * 128 + kt * 32 + q * 8];
    v4f acc2[4] = {};
#pragma unroll
    for (int kt = 0; kt < 4; kt++)
#pragma unroll
        for (int mt = 0; mt < 4; mt++) {
            v8s a = *(const v8s*)&za[(mt * 16 + l15) * 136 + kt * 32 + q * 8];
            acc2[mt] = MFMA(a, b2[kt], acc2[mt]);
        }

    {
        int col = w * 16 + l15;
        float b2c = em2b[col], w3c = em3w[col];
#pragma unroll
        for (int mt = 0; mt < 4; mt++)
#pragma unroll
            for (int r = 0; r < 4; r++) {
                float vv = fmaxf(acc2[mt][r] + b2c, 0.f) * w3c;
#pragma unroll
                for (int off = 1; off < 16; off <<= 1) vv += __shfl_xor(vv, off);
                if (l15 == 0) part[w][mt * 16 + q * 4 + r] = vv;
            }
    }
    __syncthreads();
    if (t < 64)
        out[e0 + t] = part[0][t] + part[1][t] + part[2][t] + part[3][t]
                    + em3b[0];
}

// ------------------------------------------------------------ launch
extern "C" __attribute__((visibility("default")))
void kernel_launch(void* const* d_in, const int* in_sizes, int n_in,
                   void* d_out, int out_size, void* d_ws, size_t ws_size,
                   hipStream_t stream) {
    float* out = (float*)d_out;

    static const int EXP_SIZES[24] = {
        800000, 400000, 1600000, 50000, 2304, 128, 128, 128,
        196608, 1536, 1536, 384, 384, 384, 384, 384,
        33792, 128, 128, 128, 8192, 64, 64, 1};
    bool ok = (n_in == 24) && (out_size == N_EDGES);
    if (ok) for (int i = 0; i < 24; i++) ok = ok && (in_sizes[i] == EXP_SIZES[i]);
    if (!ok) {
        k_fill<<<(out_size + 255) / 256, 256, 0, stream>>>(out, out_size, 4.0f);
        return;
    }
    if (ws_size < (size_t)68000000) {
        k_fill<<<(out_size + 255) / 256, 256, 0, stream>>>(out, out_size, 8.0f);
        return;
    }

    const int* ei    = (const int*)d_in[1];
    const int* shock = (const int*)d_in[3];

    char* ws = (char*)d_ws;
    unsigned short* h_bf  = (unsigned short*)(ws + 0);          // 12,800,000
    unsigned short* xh    = (unsigned short*)(ws + 12800000);   // 51,200,000
    unsigned short* UV    = xh;   // aliases xh (xh dead before k_uvgemm)
    float* al_s    = (float*)(ws + 64000000);
    float* al_d    = (float*)(ws + 64800000);
    float* down    = (float*)(ws + 65600000);
    int*   deg     = (int*)  (ws + 65800000);
    int*   row_st  = (int*)  (ws + 66000000);
    int*   fill    = (int*)  (ws + 66200064);
    int*   csr_src = (int*)  (ws + 66400064);
    int*   flag    = (int*)  (ws + 67400064);
    unsigned short* gwt = (unsigned short*)(ws + 67400128);     // 393,216
    unsigned short* uvt = (unsigned short*)(ws + 67793344);     // 65,536
    unsigned short* w2t = (unsigned short*)(ws + 67858880);     // 16,384
    float* pool    = (float*)(ws + 67875264);                   // 9,224 f32
    int*   bsum    = (int*)  (ws + 67912160);                   // 784 B

    float* cencw = pool + 0;    float* cencb = pool + 2304;
    float* cenlg = pool + 2432; float* cenlb = pool + 2560;
    float* casrc = pool + 2688; float* cadst = pool + 4224;
    float* cbias = pool + 5760; float* cbng  = pool + 6144;
    float* cbnb  = pool + 6528; float* cbnm  = pool + 6912;
    float* cbnv  = pool + 7296; float* cem1b = pool + 7680;
    float* cemlg = pool + 7808; float* cemlb = pool + 7936;
    float* cem2b = pool + 8064; float* cem3w = pool + 8128;
    float* cem3b = pool + 8192;
    float* w1e   = pool + 8200;   // [8][128] fp32

    k_detect<<<1, 64, 0, stream>>>((const unsigned short*)d_in[0], flag);

    PrepArgs pa;
    pa.encw = d_in[4];  pa.encb = d_in[5];  pa.enlg = d_in[6];  pa.enlb = d_in[7];
    pa.gatw = d_in[8];  pa.asrc = d_in[9];  pa.adst = d_in[10]; pa.bias = d_in[11];
    pa.bng  = d_in[12]; pa.bnb  = d_in[13]; pa.bnm  = d_in[14]; pa.bnv  = d_in[15];
    pa.em1w = d_in[16]; pa.em1b = d_in[17]; pa.emlg = d_in[18]; pa.emlb = d_in[19];
    pa.em2w = d_in[20]; pa.em2b = d_in[21]; pa.em3w = d_in[22]; pa.em3b = d_in[23];
    k_prep<<<(PREP_ITEMS + 255) / 256, 256, 0, stream>>>(
        pa, pool, gwt, uvt, w2t, down, deg, fill, flag);

    k_graph<<<(ETOT + 255) / 256, 256, 0, stream>>>(ei, shock, down, deg);
    k_scan1<<<NSB, 256, 0, stream>>>(deg, bsum);
    k_scan2<<<NSB, 256, 0, stream>>>(deg, bsum, row_st);
    k_csr<<<(ETOT + 255) / 256, 256, 0, stream>>>(ei, row_st, fill, csr_src);
    k_encoder<<<N_NODES / 4, 256, 0, stream>>>(
        d_in[0], flag, shock, down, cencw, cencb, cenlg, cenlb, h_bf);
    for (int i = 0; i < 3; i++) {
        k_gemm<<<dim3(782, 4), 256, 0, stream>>>(
            h_bf, gwt + (size_t)i * 65536, casrc + i * 512, cadst + i * 512,
            xh, al_s, al_d);
        k_aggregate<<<N_NODES / 4, 256, 0, stream>>>(
            xh, al_s, al_d, row_st, csr_src,
            cbias + i * 128, cbng + i * 128, cbnb + i * 128,
            cbnm + i * 128, cbnv + i * 128, h_bf, (i < 2) ? 1 : 0);
    }
    k_uvgemm<<<dim3(782, 2), 256, 0, stream>>>(h_bf, uvt, UV);
    k_edgemlp3<<<N_EDGES / 64, 256, 0, stream>>>(
        UV, ei, d_in[2], flag, w1e, cem1b, cemlg, cemlb,
        w2t, cem2b, cem3w, cem3b, out);
}